// Round 1
// 4975.597 us; speedup vs baseline: 1.6400x; 1.6400x over previous
//
#include <hip/hip_runtime.h>

typedef unsigned short ushort_t;
typedef unsigned int uint_t;
typedef __attribute__((ext_vector_type(8))) short short8;   // 8 bf16 (4 VGPR) MFMA frag
typedef __attribute__((ext_vector_type(4))) float f32x4;    // MFMA accumulator frag

#define B_    16
#define L_    4096
#define H_    256
#define N_    32
#define DIN_  257
#define DOUT_ 257
#define NL_   4
#define Q_    128
#define NC_   32                 // L_/Q_
#define BL_   (B_*L_)            // 65536
#define NH_   (N_*H_)            // 8192
#define PLANE_ 16777216          // BL_*H_
#define SSZ_  4194304            // B_*NC_*N_*H_ (elements)

__device__ __forceinline__ float bfu(ushort_t u) {
    union { uint_t i; float f; } v; v.i = ((uint_t)u) << 16; return v.f;
}
__device__ __forceinline__ ushort_t f2bf(float f) {
    union { float f; uint_t i; } v; v.f = f;
    uint_t x = v.i;
    return (ushort_t)((x + 0x7FFFu + ((x >> 16) & 1u)) >> 16);
}
__device__ __forceinline__ uint2 pack4(float a, float b, float c, float d) {
    uint2 r;
    r.x = (uint_t)f2bf(a) | ((uint_t)f2bf(b) << 16);
    r.y = (uint_t)f2bf(c) | ((uint_t)f2bf(d) << 16);
    return r;
}
// dtype-flexible external-input load: f32!=0 -> fp32, else bf16
__device__ __forceinline__ float ldi(const void* p, size_t i, int f32) {
    return f32 ? ((const float*)p)[i] : bfu(((const ushort_t*)p)[i]);
}

// async global->LDS, 16B per lane (dest = wave-uniform base + lane*16)
__device__ __forceinline__ void gl16(const ushort_t* g, ushort_t* l) {
    __builtin_amdgcn_global_load_lds(
        (const __attribute__((address_space(1))) uint_t*)g,
        (__attribute__((address_space(3))) uint_t*)l, 16, 0, 0);
}

// load 8 source weights (fp32 or bf16) as packed bf16x8 (uint4)
__device__ __forceinline__ uint4 ld8bf(const void* W, size_t eoff, int f32) {
    uint4 r;
    if (f32) {
        const float* p = (const float*)W + eoff;
        float4 a = *(const float4*)p;
        float4 b = *(const float4*)(p + 4);
        r.x = (uint_t)f2bf(a.x) | ((uint_t)f2bf(a.y) << 16);
        r.y = (uint_t)f2bf(a.z) | ((uint_t)f2bf(a.w) << 16);
        r.z = (uint_t)f2bf(b.x) | ((uint_t)f2bf(b.y) << 16);
        r.w = (uint_t)f2bf(b.z) | ((uint_t)f2bf(b.w) << 16);
    } else {
        r = *(const uint4*)((const ushort_t*)W + eoff);
    }
    return r;
}

// negate 8 packed bf16 (sign-bit flip) -> used for -xi*Wi accumulation
__device__ __forceinline__ short8 negbf(short8 v) {
    short8 r;
#pragma unroll
    for (int i = 0; i < 8; ++i) r[i] = (short)(v[i] ^ (short)0x8000);
    return r;
}

#define MFMA16(a, b, c) __builtin_amdgcn_mfma_f32_16x16x32_bf16((a), (b), (c), 0, 0, 0)

// ---------------- dtype probe --------------------------------------------
__global__ void probe_kernel(const void* __restrict__ x, int* __restrict__ flag) {
    __shared__ int cnt;
    if (threadIdx.x == 0) cnt = 0;
    __syncthreads();
    uint_t w = ((const uint_t*)x)[threadIdx.x];
    float f = bfu((ushort_t)(w & 0xFFFF));
    float a = fabsf(f);
    if (a > 1e-5f && a < 100.f) atomicAdd(&cnt, 1);
    __syncthreads();
    if (threadIdx.x == 0) *flag = (cnt > 128) ? 0 : 1;  // 0 = bf16, 1 = fp32
}

// ---------------- SSM parameter precompute -------------------------------
__global__ __launch_bounds__(256) void param_kernel(
        const void* __restrict__ log_dt, const void* __restrict__ lAr,
        const void* __restrict__ Aim, const void* __restrict__ C2,
        float* __restrict__ params, const int* __restrict__ dfl) {
    int f32 = *dfl;
    int idx = blockIdx.x * 256 + threadIdx.x;   // over NL_*2*N_*H_ = 65536
    int h  = idx & (H_ - 1);
    int n  = (idx >> 8) & (N_ - 1);
    int lb = idx >> 13;                          // layer*2+branch
    float dt = expf(ldi(log_dt, lb * H_ + h, f32));
    size_t pin = (size_t)(lb * H_ + h) * N_ + n;
    float Ar = -expf(ldi(lAr, pin, f32));
    float Ai = ldi(Aim, pin, f32);
    float Cr = ldi(C2, pin * 2, f32), Ci = ldi(C2, pin * 2 + 1, f32);
    float dr = Ar * dt, di = Ai * dt;
    float e  = expf(dr);
    float wr = e * cosf(di), wi = e * sinf(di);
    float Er = wr - 1.0f, Ei = wi;               // exp(dtA) - 1
    float inv = 1.0f / (Ar * Ar + Ai * Ai);
    float Fr = (Er * Ar + Ei * Ai) * inv;        // (exp(dtA)-1)/A
    float Fi = (Ei * Ar - Er * Ai) * inv;
    float ctr = 2.0f * (Cr * Fr - Ci * Fi);
    float cti = 2.0f * (Cr * Fi + Ci * Fr);
    float eq = expf((float)Q_ * dr);
    float ph = (float)Q_ * di;
    float wqr = eq * cosf(ph), wqi = eq * sinf(ph);
    float* pb = params + (size_t)lb * 6 * NH_;
    int o = n * H_ + h;
    pb[0 * NH_ + o] = wr;  pb[1 * NH_ + o] = wi;
    pb[2 * NH_ + o] = ctr; pb[3 * NH_ + o] = cti;
    pb[4 * NH_ + o] = wqr; pb[5 * NH_ + o] = wqi;
}

// ---------------- Encoder: complex GEMM (BL x 257) x (257 -> 256) --------
__global__ __launch_bounds__(256) void enc_gemm(
        const void* __restrict__ x, const void* __restrict__ Wr,
        const void* __restrict__ Wi, const void* __restrict__ br,
        const void* __restrict__ bi, ushort_t* __restrict__ xr,
        ushort_t* __restrict__ xi, const int* __restrict__ dfl) {
    __shared__ float Ar_s[16][64], Ai_s[16][64], Wr_s[16][64], Wi_s[16][64];
    int f32 = *dfl;
    int m0 = blockIdx.x * 64, n0 = blockIdx.y * 64;
    int tid = threadIdx.x;
    int ty = tid >> 4, tx = tid & 15;
    float accR[4][4] = {{0}}, accI[4][4] = {{0}};
    for (int k0 = 0; k0 < DIN_; k0 += 16) {
#pragma unroll
        for (int j = 0; j < 4; ++j) {            // A tile: 1024 (re,im) pairs
            int p = tid * 4 + j;
            int m = p >> 4, kk = p & 15;
            int k = k0 + kk;
            float r = 0.f, im = 0.f;
            if (k < DIN_) {
                size_t pi = (size_t)(m0 + m) * DIN_ + k;
                if (f32) {
                    float2 v = ((const float2*)x)[pi];
                    r = v.x; im = v.y;
                } else {
                    uint_t v = ((const uint_t*)x)[pi];
                    r  = bfu((ushort_t)(v & 0xFFFF));
                    im = bfu((ushort_t)(v >> 16));
                }
            }
            Ar_s[kk][m] = r; Ai_s[kk][m] = im;
        }
        {
            int n = tid >> 2, kpos = (tid & 3) * 4;
#pragma unroll
            for (int j = 0; j < 4; ++j) {
                int k = k0 + kpos + j;
                float wr_ = 0.f, wi_ = 0.f;
                if (k < DIN_) {
                    wr_ = ldi(Wr, (size_t)(n0 + n) * DIN_ + k, f32);
                    wi_ = ldi(Wi, (size_t)(n0 + n) * DIN_ + k, f32);
                }
                Wr_s[kpos + j][n] = wr_; Wi_s[kpos + j][n] = wi_;
            }
        }
        __syncthreads();
#pragma unroll
        for (int kk = 0; kk < 16; ++kk) {
            float ar[4], ai[4], ur[4], ui[4];
#pragma unroll
            for (int i = 0; i < 4; ++i) {
                ar[i] = Ar_s[kk][ty * 4 + i]; ai[i] = Ai_s[kk][ty * 4 + i];
                ur[i] = Wr_s[kk][tx * 4 + i]; ui[i] = Wi_s[kk][tx * 4 + i];
            }
#pragma unroll
            for (int i = 0; i < 4; ++i)
#pragma unroll
                for (int j = 0; j < 4; ++j) {
                    accR[i][j] = fmaf(ar[i], ur[j], fmaf(-ai[i], ui[j], accR[i][j]));
                    accI[i][j] = fmaf(ar[i], ui[j], fmaf( ai[i], ur[j], accI[i][j]));
                }
        }
        __syncthreads();
    }
    float bR[4], bI[4];
#pragma unroll
    for (int j = 0; j < 4; ++j) {
        bR[j] = ldi(br, n0 + tx * 4 + j, f32);
        bI[j] = ldi(bi, n0 + tx * 4 + j, f32);
    }
#pragma unroll
    for (int i = 0; i < 4; ++i) {
        size_t row = (size_t)(m0 + ty * 4 + i);
        size_t off = row * H_ + n0 + tx * 4;
        *(uint2*)(xr + off) = pack4(accR[i][0] + bR[0], accR[i][1] + bR[1],
                                    accR[i][2] + bR[2], accR[i][3] + bR[3]);
        *(uint2*)(xi + off) = pack4(accI[i][0] + bI[0], accI[i][1] + bI[1],
                                    accI[i][2] + bI[2], accI[i][3] + bI[3]);
    }
}

// ---------------- Pass A: per-chunk local state inject (states -> bf16) ---
__global__ __launch_bounds__(256) void pass_a(
        const ushort_t* __restrict__ U, const float* __restrict__ P, ushort_t* __restrict__ S) {
    int c = blockIdx.x, b = blockIdx.y, h = threadIdx.x;
    float wr[N_], wi[N_], sr[N_], si[N_];
#pragma unroll
    for (int n = 0; n < N_; ++n) {
        wr[n] = P[n * H_ + h]; wi[n] = P[NH_ + n * H_ + h];
        sr[n] = 0.f; si[n] = 0.f;
    }
    const ushort_t* u = U + (size_t)(b * L_ + c * Q_) * H_ + h;
    float uvn = bfu(u[0]);
    for (int t = 0; t < Q_; ++t) {
        float uv = uvn;
        int tn = (t + 1 < Q_) ? t + 1 : t;
        uvn = bfu(u[(size_t)tn * H_]);
#pragma unroll
        for (int n = 0; n < N_; ++n) {
            float nr = fmaf(wr[n], sr[n], fmaf(-wi[n], si[n], uv));
            si[n] = fmaf(wr[n], si[n], wi[n] * sr[n]);
            sr[n] = nr;
        }
    }
    size_t o = (size_t)(b * NC_ + c) * N_ * H_ + h;
#pragma unroll
    for (int n = 0; n < N_; ++n) {
        S[o + n * H_] = f2bf(sr[n]);
        S[o + n * H_ + SSZ_] = f2bf(si[n]);
    }
}

// ---------------- Pass B: chunk-level carry scan (in-place -> init state) -
__global__ __launch_bounds__(256) void pass_b(
        const float* __restrict__ P, ushort_t* __restrict__ S) {
    int n = blockIdx.x, b = blockIdx.y, h = threadIdx.x;
    float wqr = P[4 * NH_ + n * H_ + h], wqi = P[5 * NH_ + n * H_ + h];
    float Xr = 0.f, Xi = 0.f;
    for (int c = 0; c < NC_; ++c) {
        size_t idx = ((size_t)(b * NC_ + c) * N_ + n) * H_ + h;
        float lr = bfu(S[idx]), li = bfu(S[idx + SSZ_]);
        S[idx] = f2bf(Xr); S[idx + SSZ_] = f2bf(Xi);   // init state for chunk c
        float nr = fmaf(wqr, Xr, fmaf(-wqi, Xi, lr));
        Xi = fmaf(wqr, Xi, fmaf(wqi, Xr, li));
        Xr = nr;
    }
}

// ---------------- Pass C: scan w/ init + y=conv+D*u -> gelu --------------
__global__ __launch_bounds__(256) void pass_c(
        const ushort_t* __restrict__ U, const float* __restrict__ P,
        const ushort_t* __restrict__ S, const void* __restrict__ Dp, int doff,
        ushort_t* __restrict__ G, const int* __restrict__ dfl) {
    int f32 = *dfl;
    int c = blockIdx.x, b = blockIdx.y;
    int tid = threadIdx.x;
    int h = blockIdx.z * 128 + (tid >> 1);
    int nb = (tid & 1) * 16;
    float wr[16], wi[16], cr[16], ci[16], sr[16], si[16];
#pragma unroll
    for (int i = 0; i < 16; ++i) {
        int o = (nb + i) * H_ + h;
        wr[i] = P[o]; wi[i] = P[NH_ + o];
        cr[i] = P[2 * NH_ + o]; ci[i] = P[3 * NH_ + o];
    }
    size_t so = (size_t)(b * NC_ + c) * N_ * H_ + h;
#pragma unroll
    for (int i = 0; i < 16; ++i) {
        sr[i] = bfu(S[so + (nb + i) * H_]);
        si[i] = bfu(S[so + (nb + i) * H_ + SSZ_]);
    }
    float Dv = ldi(Dp, (size_t)doff + h, f32);
    const ushort_t* u = U + (size_t)(b * L_ + c * Q_) * H_ + h;
    ushort_t* g = G + (size_t)(b * L_ + c * Q_) * H_ + h;
    float uvn = bfu(u[0]);
    for (int t = 0; t < Q_; ++t) {
        float uv = uvn;
        int tn = (t + 1 < Q_) ? t + 1 : t;
        uvn = bfu(u[(size_t)tn * H_]);
        float a0 = 0.f, a1 = 0.f;
#pragma unroll
        for (int i = 0; i < 16; ++i) {
            float nr = fmaf(wr[i], sr[i], fmaf(-wi[i], si[i], uv));
            si[i] = fmaf(wr[i], si[i], wi[i] * sr[i]);
            sr[i] = nr;
            if (i & 1) a1 = fmaf(cr[i], sr[i], fmaf(-ci[i], si[i], a1));
            else       a0 = fmaf(cr[i], sr[i], fmaf(-ci[i], si[i], a0));
        }
        float acc = a0 + a1;
        acc += __shfl_xor(acc, 1, 64);           // combine the two 16-state halves
        float y = fmaf(Dv, uv, acc);
        float ge = 0.5f * y * (1.0f + erff(y * 0.70710678118654752f));
        if ((tid & 1) == 0) g[(size_t)t * H_] = f2bf(ge);
    }
}

// ---------------- Wout GEMM (MFMA) + bias + GLU, accumulate into z -------
// C = Gb(128xK) x W^T. B-tile rows 0..63 = 'a' channels n0..n0+63,
// rows 64..127 = 'g' channels 256+n0.. ; GLU fused in epilogue.
// LDS tiles are [row][64] bf16 (128B rows) with T2 XOR swizzle
// (byte ^= (row&7)<<4) to kill the 16-way ds_read_b128 bank conflict.
// mode: 0 = store, 1 = add, 2 = sub
__global__ __launch_bounds__(256) void wout_gemm(
        const ushort_t* __restrict__ Gb, const void* __restrict__ W, size_t woff,
        const void* __restrict__ bo, int boff, ushort_t* __restrict__ Z, int mode,
        const int* __restrict__ dfl) {
    __shared__ __align__(16) ushort_t As[8192];   // 128 x 64 bf16 (swizzled)
    __shared__ __align__(16) ushort_t Bs[8192];   // 128 x 64 bf16 (swizzled)
    int f32 = *dfl;
    int m0 = blockIdx.x * 128, n0 = blockIdx.y * 64;
    int tid = threadIdx.x;
    int w = tid >> 6, l = tid & 63;
    int rb = w * 32;                              // wave's 32-row slice
    int lr = l & 15, lk = (l >> 4) << 4;          // frag row-in-16 / k-octet byte
    int lsw = (l & 7) << 4;                       // read-side swizzle
    // A-stage (global_load_lds, pre-swizzled source):
    int arow = tid >> 3;                          // 0..31 (+ch*32)
    int acb  = ((tid & 7) << 4) ^ ((arow & 7) << 4);  // logical colbyte at dest slot
    // B-stage (reg-staged, handles fp32-or-bf16 weights):
    int brow = tid >> 1;                          // 0..127
    int bhalf = (tid & 1) << 6;                   // colbyte 0 or 64
    int bsw = (brow & 7) << 4;
    int wrow = (brow < 64) ? (n0 + brow) : (192 + n0 + brow);  // a rows / g rows
    f32x4 z4 = {0.f, 0.f, 0.f, 0.f};
    f32x4 acc[2][8];
#pragma unroll
    for (int mi = 0; mi < 2; ++mi)
#pragma unroll
        for (int nj = 0; nj < 8; ++nj) acc[mi][nj] = z4;

    for (int k0 = 0; k0 < H_; k0 += 64) {
        if (k0) __syncthreads();
        {   // A: 128x64 bf16, 4 chunks of 256 lanes x 16B
            const ushort_t* src = Gb + (size_t)(m0 + arow) * H_ + k0 + (acb >> 1);
            ushort_t* dst = As + tid * 8;
#pragma unroll
            for (int ch = 0; ch < 4; ++ch)
                gl16(src + (size_t)ch * 32 * H_, dst + ch * 2048);
        }
        {   // B: W rows -> swizzled LDS (64B per thread)
            size_t wb = woff + (size_t)wrow * H_ + k0;
            char* bp = (char*)Bs + brow * 128;
#pragma unroll
            for (int cc = 0; cc < 4; ++cc) {
                int cb = bhalf + cc * 16;
                uint4 v = ld8bf(W, wb + (cb >> 1), f32);
                *(uint4*)(bp + (cb ^ bsw)) = v;
            }
        }
        __syncthreads();
#pragma unroll
        for (int ks = 0; ks < 2; ++ks) {
            int off = (ks * 64 + lk) ^ lsw;
            short8 a0 = *(const short8*)((const char*)As + (rb + lr) * 128 + off);
            short8 a1 = *(const short8*)((const char*)As + (rb + 16 + lr) * 128 + off);
#pragma unroll
            for (int nj = 0; nj < 8; ++nj) {
                short8 bv = *(const short8*)((const char*)Bs + (nj * 16 + lr) * 128 + off);
                acc[0][nj] = MFMA16(a0, bv, acc[0][nj]);
                acc[1][nj] = MFMA16(a1, bv, acc[1][nj]);
            }
        }
    }
    float ba[4], bg[4];
#pragma unroll
    for (int nj = 0; nj < 4; ++nj) {
        ba[nj] = ldi(bo, (size_t)boff + n0 + nj * 16 + lr, f32);
        bg[nj] = ldi(bo, (size_t)boff + 256 + n0 + nj * 16 + lr, f32);
    }
#pragma unroll
    for (int mi = 0; mi < 2; ++mi)
#pragma unroll
        for (int nj = 0; nj < 4; ++nj)
#pragma unroll
            for (int r = 0; r < 4; ++r) {
                float av = acc[mi][nj][r] + ba[nj];
                float gv = acc[mi][nj + 4][r] + bg[nj];
                float s = av * (1.0f / (1.0f + expf(-gv)));
                int row = m0 + rb + mi * 16 + ((l >> 4) << 2) + r;
                size_t zo = (size_t)row * H_ + n0 + nj * 16 + lr;
                if (mode == 0)      Z[zo] = f2bf(s);
                else if (mode == 1) Z[zo] = f2bf(bfu(Z[zo]) + s);
                else                Z[zo] = f2bf(bfu(Z[zo]) - s);
            }
}

// ---------------- residual + LayerNorm (both real & imag) ----------------
__global__ __launch_bounds__(256) void combine_ln(
        ushort_t* __restrict__ xr, ushort_t* __restrict__ xi,
        const ushort_t* __restrict__ zr, const ushort_t* __restrict__ zi,
        const void* __restrict__ gamma, const void* __restrict__ beta, int layer,
        const int* __restrict__ dfl) {
    __shared__ float red[4][4];
    int f32 = *dfl;
    int l = blockIdx.x, b = blockIdx.y, h = threadIdx.x;
    size_t row = (size_t)(b * L_ + l) * H_ + h;
    float vr = bfu(xr[row]) + bfu(zr[row]);
    float vi = bfu(xi[row]) + bfu(zi[row]);
    float s0 = vr, s1 = vr * vr, s2 = vi, s3 = vi * vi;
#pragma unroll
    for (int off = 32; off >= 1; off >>= 1) {
        s0 += __shfl_xor(s0, off, 64); s1 += __shfl_xor(s1, off, 64);
        s2 += __shfl_xor(s2, off, 64); s3 += __shfl_xor(s3, off, 64);
    }
    int wv = h >> 6;
    if ((h & 63) == 0) { red[wv][0] = s0; red[wv][1] = s1; red[wv][2] = s2; red[wv][3] = s3; }
    __syncthreads();
    float S0 = red[0][0] + red[1][0] + red[2][0] + red[3][0];
    float S1 = red[0][1] + red[1][1] + red[2][1] + red[3][1];
    float S2 = red[0][2] + red[1][2] + red[2][2] + red[3][2];
    float S3 = red[0][3] + red[1][3] + red[2][3] + red[3][3];
    const float invH = 1.0f / 256.0f;
    float mur = S0 * invH, varr = S1 * invH - mur * mur;
    float mui = S2 * invH, vari = S3 * invH - mui * mui;
    float gr = ldi(gamma, (size_t)(layer * 2 + 0) * H_ + h, f32);
    float br_ = ldi(beta, (size_t)(layer * 2 + 0) * H_ + h, f32);
    float gi = ldi(gamma, (size_t)(layer * 2 + 1) * H_ + h, f32);
    float bi_ = ldi(beta, (size_t)(layer * 2 + 1) * H_ + h, f32);
    xr[row] = f2bf((vr - mur) * rsqrtf(varr + 1e-5f) * gr + br_);
    xi[row] = f2bf((vi - mui) * rsqrtf(vari + 1e-5f) * gi + bi_);
}

// ---------------- Decoder: complex GEMM (MFMA) (BL x 256) -> 257 ---------
// accR = xr*Wr^T - xi*Wi^T ; accI = xr*Wi^T + xi*Wr^T
// Subtraction via in-register bf16 sign-flip of the Wi fragment.
// N-ragged edge (257): B rows >= DOUT_ zero-filled, stores masked.
__global__ __launch_bounds__(256) void dec_gemm(
        const ushort_t* __restrict__ xr, const ushort_t* __restrict__ xi,
        const void* __restrict__ Wr, const void* __restrict__ Wi,
        const void* __restrict__ br, const void* __restrict__ bi,
        void* __restrict__ out, const int* __restrict__ dfl) {
    __shared__ __align__(16) ushort_t Ars[8192];  // xr tile 128x64
    __shared__ __align__(16) ushort_t Ais[8192];  // xi tile 128x64
    __shared__ __align__(16) ushort_t Brs[4096];  // Wr tile  64x64
    __shared__ __align__(16) ushort_t Bis[4096];  // Wi tile  64x64
    int f32 = *dfl;
    int m0 = blockIdx.x * 128, n0 = blockIdx.y * 64;
    int tid = threadIdx.x;
    int w = tid >> 6, l = tid & 63;
    int rb = w * 32;
    int lr = l & 15, lk = (l >> 4) << 4, lsw = (l & 7) << 4;
    int arow = tid >> 3;
    int acb  = ((tid & 7) << 4) ^ ((arow & 7) << 4);
    int brow = tid >> 2;                          // 0..63
    int bq   = (tid & 3) << 5;                    // colbyte 0/32/64/96
    int bsw  = (brow & 7) << 4;
    int wrow = n0 + brow;
    bool bvalid = wrow < DOUT_;
    uint4 zz; zz.x = zz.y = zz.z = zz.w = 0u;
    f32x4 z4 = {0.f, 0.f, 0.f, 0.f};
    f32x4 aR[2][4], aI[2][4];
#pragma unroll
    for (int mi = 0; mi < 2; ++mi)
#pragma unroll
        for (int nj = 0; nj < 4; ++nj) { aR[mi][nj] = z4; aI[mi][nj] = z4; }

    for (int k0 = 0; k0 < H_; k0 += 64) {
        if (k0) __syncthreads();
        {   // A: xr and xi tiles via global_load_lds (pre-swizzled source)
            size_t so = (size_t)(m0 + arow) * H_ + k0 + (acb >> 1);
            ushort_t* dr = Ars + tid * 8;
            ushort_t* di = Ais + tid * 8;
#pragma unroll
            for (int ch = 0; ch < 4; ++ch) {
                gl16(xr + so + (size_t)ch * 32 * H_, dr + ch * 2048);
                gl16(xi + so + (size_t)ch * 32 * H_, di + ch * 2048);
            }
        }
        {   // B: Wr/Wi rows -> swizzled LDS, zero-fill past row 256
            size_t wb = (size_t)wrow * H_ + k0 + (bq >> 1);
            char* pr_ = (char*)Brs + brow * 128;
            char* pi_ = (char*)Bis + brow * 128;
#pragma unroll
            for (int cc = 0; cc < 2; ++cc) {
                int cb = bq + cc * 16;
                uint4 vr = zz, vi = zz;
                if (bvalid) {
                    vr = ld8bf(Wr, wb + cc * 8, f32);
                    vi = ld8bf(Wi, wb + cc * 8, f32);
                }
                *(uint4*)(pr_ + (cb ^ bsw)) = vr;
                *(uint4*)(pi_ + (cb ^ bsw)) = vi;
            }
        }
        __syncthreads();
#pragma unroll
        for (int ks = 0; ks < 2; ++ks) {
            int off = (ks * 64 + lk) ^ lsw;
            short8 x0 = *(const short8*)((const char*)Ars + (rb + lr) * 128 + off);
            short8 x1 = *(const short8*)((const char*)Ars + (rb + 16 + lr) * 128 + off);
            short8 y0 = *(const short8*)((const char*)Ais + (rb + lr) * 128 + off);
            short8 y1 = *(const short8*)((const char*)Ais + (rb + 16 + lr) * 128 + off);
#pragma unroll
            for (int nj = 0; nj < 4; ++nj) {
                short8 wr_ = *(const short8*)((const char*)Brs + (nj * 16 + lr) * 128 + off);
                short8 wi_ = *(const short8*)((const char*)Bis + (nj * 16 + lr) * 128 + off);
                short8 wn = negbf(wi_);
                aR[0][nj] = MFMA16(x0, wr_, aR[0][nj]);
                aR[0][nj] = MFMA16(y0, wn,  aR[0][nj]);
                aR[1][nj] = MFMA16(x1, wr_, aR[1][nj]);
                aR[1][nj] = MFMA16(y1, wn,  aR[1][nj]);
                aI[0][nj] = MFMA16(x0, wi_, aI[0][nj]);
                aI[0][nj] = MFMA16(y0, wr_, aI[0][nj]);
                aI[1][nj] = MFMA16(x1, wi_, aI[1][nj]);
                aI[1][nj] = MFMA16(y1, wr_, aI[1][nj]);
            }
        }
    }
#pragma unroll
    for (int nj = 0; nj < 4; ++nj) {
        int col = n0 + nj * 16 + lr;
        if (col < DOUT_) {
            float bR = ldi(br, col, f32), bI = ldi(bi, col, f32);
#pragma unroll
            for (int mi = 0; mi < 2; ++mi)
#pragma unroll
                for (int r = 0; r < 4; ++r) {
                    int row = m0 + rb + mi * 16 + ((l >> 4) << 2) + r;
                    size_t pi = (size_t)row * DOUT_ + col;
                    float re = aR[mi][nj][r] + bR;
                    float im = aI[mi][nj][r] + bI;
                    if (f32) {
                        ((float2*)out)[pi] = make_float2(re, im);
                    } else {
                        ((uint_t*)out)[pi] = (uint_t)f2bf(re) | ((uint_t)f2bf(im) << 16);
                    }
                }
        }
    }
}

// -------------------------------------------------------------------------
extern "C" void kernel_launch(void* const* d_in, const int* in_sizes, int n_in,
                              void* d_out, int out_size, void* d_ws, size_t ws_size,
                              hipStream_t stream) {
    const void* x      = d_in[0];
    const void* enc_Wr = d_in[1];
    const void* enc_Wi = d_in[2];
    const void* enc_br = d_in[3];
    const void* enc_bi = d_in[4];
    const void* log_dt = d_in[5];
    const void* lAr    = d_in[6];
    const void* Aim    = d_in[7];
    const void* C2     = d_in[8];
    const void* Dp     = d_in[9];
    const void* Wout   = d_in[10];
    const void* bout   = d_in[11];
    const void* gamma  = d_in[12];
    const void* beta   = d_in[13];
    const void* dec_Wr = d_in[14];
    const void* dec_Wi = d_in[15];
    const void* dec_br = d_in[16];
    const void* dec_bi = d_in[17];

    // ws layout (~113.6 MiB):
    //   xr (32M) | xi (32M) | gb (32M) | st bf16 (16M) | flag | pr fp32 (1.5M)
    // zr/zi live in d_out (dead until dec_gemm rewrites every element last)
    ushort_t* xr = (ushort_t*)d_ws;
    ushort_t* xi = xr + (size_t)PLANE_;
    ushort_t* gb = xi + (size_t)PLANE_;
    ushort_t* st = gb + (size_t)PLANE_;
    int*      fl = (int*)(st + (size_t)2 * SSZ_);
    float*    pr = (float*)(fl + 64);            // 256-byte pad for alignment
    ushort_t* zr = (ushort_t*)d_out;
    ushort_t* zi = zr + (size_t)PLANE_;

    probe_kernel<<<1, 256, 0, stream>>>(x, fl);
    param_kernel<<<256, 256, 0, stream>>>(log_dt, lAr, Aim, C2, pr, fl);
    enc_gemm<<<dim3(BL_ / 64, H_ / 64), 256, 0, stream>>>(x, enc_Wr, enc_Wi, enc_br, enc_bi, xr, xi, fl);

    for (int l = 0; l < NL_; ++l) {
        // zr = sr(xr) - si(xi);  zi = sr(xi) + si(xr)
        struct App { int br; const ushort_t* U; ushort_t* Zt; int mode; };
        App apps[4] = {
            {0, xr, zr, 0},   // sr(xr) -> zr (store)
            {1, xi, zr, 2},   // si(xi) -> zr (sub)
            {0, xi, zi, 0},   // sr(xi) -> zi (store)
            {1, xr, zi, 1},   // si(xr) -> zi (add)
        };
        for (int a = 0; a < 4; ++a) {
            const float* P = pr + (size_t)(l * 2 + apps[a].br) * 6 * NH_;
            pass_a<<<dim3(NC_, B_), 256, 0, stream>>>(apps[a].U, P, st);
            pass_b<<<dim3(N_, B_), 256, 0, stream>>>(P, st);
            pass_c<<<dim3(NC_, B_, 2), 256, 0, stream>>>(apps[a].U, P, st,
                    Dp, (l * 2 + apps[a].br) * H_, gb, fl);
            wout_gemm<<<dim3(BL_ / 128, H_ / 64), 256, 0, stream>>>(gb,
                    Wout, (size_t)(l * 2 + apps[a].br) * 512 * H_,
                    bout, (l * 2 + apps[a].br) * 512,
                    apps[a].Zt, apps[a].mode, fl);
        }
        combine_ln<<<dim3(L_, B_), 256, 0, stream>>>(xr, xi, zr, zi, gamma, beta, l, fl);
    }

    dec_gemm<<<dim3(BL_ / 128, (DOUT_ + 63) / 64), 256, 0, stream>>>(
            xr, xi, dec_Wr, dec_Wi, dec_br, dec_bi, d_out, fl);
}

// Round 2
// 4674.294 us; speedup vs baseline: 1.7458x; 1.0645x over previous
//
#include <hip/hip_runtime.h>

typedef unsigned short ushort_t;
typedef unsigned int uint_t;
typedef __attribute__((ext_vector_type(8))) short short8;   // 8 bf16 (4 VGPR) MFMA frag
typedef __attribute__((ext_vector_type(4))) float f32x4;    // MFMA accumulator frag

#define B_    16
#define L_    4096
#define H_    256
#define N_    32
#define DIN_  257
#define DOUT_ 257
#define NL_   4
#define Q_    128
#define NC_   32                 // L_/Q_
#define BL_   (B_*L_)            // 65536
#define NH_   (N_*H_)            // 8192
#define PLANE_ 16777216          // BL_*H_
#define SSZ_  4194304            // B_*NC_*N_*H_ (elements)
#define EPK_  520                // packed enc-weight row stride (interleaved, 16B-aligned)

__device__ __forceinline__ float bfu(ushort_t u) {
    union { uint_t i; float f; } v; v.i = ((uint_t)u) << 16; return v.f;
}
__device__ __forceinline__ ushort_t f2bf(float f) {
    union { float f; uint_t i; } v; v.f = f;
    uint_t x = v.i;
    return (ushort_t)((x + 0x7FFFu + ((x >> 16) & 1u)) >> 16);
}
__device__ __forceinline__ uint2 pack4(float a, float b, float c, float d) {
    uint2 r;
    r.x = (uint_t)f2bf(a) | ((uint_t)f2bf(b) << 16);
    r.y = (uint_t)f2bf(c) | ((uint_t)f2bf(d) << 16);
    return r;
}
// dtype-flexible external-input load: f32!=0 -> fp32, else bf16
__device__ __forceinline__ float ldi(const void* p, size_t i, int f32) {
    return f32 ? ((const float*)p)[i] : bfu(((const ushort_t*)p)[i]);
}

// async global->LDS, 16B per lane (dest = wave-uniform base + lane*16)
__device__ __forceinline__ void gl16(const ushort_t* g, ushort_t* l) {
    __builtin_amdgcn_global_load_lds(
        (const __attribute__((address_space(1))) uint_t*)g,
        (__attribute__((address_space(3))) uint_t*)l, 16, 0, 0);
}

// load 8 source weights (fp32 or bf16) as packed bf16x8 (uint4); 16B-aligned src
__device__ __forceinline__ uint4 ld8bf(const void* W, size_t eoff, int f32) {
    uint4 r;
    if (f32) {
        const float* p = (const float*)W + eoff;
        float4 a = *(const float4*)p;
        float4 b = *(const float4*)(p + 4);
        r.x = (uint_t)f2bf(a.x) | ((uint_t)f2bf(a.y) << 16);
        r.y = (uint_t)f2bf(a.z) | ((uint_t)f2bf(a.w) << 16);
        r.z = (uint_t)f2bf(b.x) | ((uint_t)f2bf(b.y) << 16);
        r.w = (uint_t)f2bf(b.z) | ((uint_t)f2bf(b.w) << 16);
    } else {
        r = *(const uint4*)((const ushort_t*)W + eoff);
    }
    return r;
}

// load 8 consecutive reals (fp32 or bf16 src) as packed bf16x8; only 8B/4B
// alignment guaranteed (odd row strides 257/514) -> float2 / uint loads
__device__ __forceinline__ uint4 ld8r(const void* x, size_t eoff, int f32) {
    uint4 r;
    if (f32) {
        const float* p = (const float*)x + eoff;       // eoff even -> 8B aligned
        float2 a = *(const float2*)p;
        float2 b = *(const float2*)(p + 2);
        float2 c = *(const float2*)(p + 4);
        float2 d = *(const float2*)(p + 6);
        r.x = (uint_t)f2bf(a.x) | ((uint_t)f2bf(a.y) << 16);
        r.y = (uint_t)f2bf(b.x) | ((uint_t)f2bf(b.y) << 16);
        r.z = (uint_t)f2bf(c.x) | ((uint_t)f2bf(c.y) << 16);
        r.w = (uint_t)f2bf(d.x) | ((uint_t)f2bf(d.y) << 16);
    } else {
        const uint_t* q = (const uint_t*)((const ushort_t*)x + eoff);  // 4B aligned
        r.x = q[0]; r.y = q[1]; r.z = q[2]; r.w = q[3];
    }
    return r;
}

// negate 8 packed bf16 (sign-bit flip) -> used for -xi*Wi accumulation
__device__ __forceinline__ short8 negbf(short8 v) {
    short8 r;
#pragma unroll
    for (int i = 0; i < 8; ++i) r[i] = (short)(v[i] ^ (short)0x8000);
    return r;
}

#define MFMA16(a, b, c) __builtin_amdgcn_mfma_f32_16x16x32_bf16((a), (b), (c), 0, 0, 0)

// ---------------- dtype probe --------------------------------------------
__global__ void probe_kernel(const void* __restrict__ x, int* __restrict__ flag) {
    __shared__ int cnt;
    if (threadIdx.x == 0) cnt = 0;
    __syncthreads();
    uint_t w = ((const uint_t*)x)[threadIdx.x];
    float f = bfu((ushort_t)(w & 0xFFFF));
    float a = fabsf(f);
    if (a > 1e-5f && a < 100.f) atomicAdd(&cnt, 1);
    __syncthreads();
    if (threadIdx.x == 0) *flag = (cnt > 128) ? 0 : 1;  // 0 = bf16, 1 = fp32
}

// ---------------- SSM parameter precompute -------------------------------
__global__ __launch_bounds__(256) void param_kernel(
        const void* __restrict__ log_dt, const void* __restrict__ lAr,
        const void* __restrict__ Aim, const void* __restrict__ C2,
        float* __restrict__ params, const int* __restrict__ dfl) {
    int f32 = *dfl;
    int idx = blockIdx.x * 256 + threadIdx.x;   // over NL_*2*N_*H_ = 65536
    int h  = idx & (H_ - 1);
    int n  = (idx >> 8) & (N_ - 1);
    int lb = idx >> 13;                          // layer*2+branch
    float dt = expf(ldi(log_dt, lb * H_ + h, f32));
    size_t pin = (size_t)(lb * H_ + h) * N_ + n;
    float Ar = -expf(ldi(lAr, pin, f32));
    float Ai = ldi(Aim, pin, f32);
    float Cr = ldi(C2, pin * 2, f32), Ci = ldi(C2, pin * 2 + 1, f32);
    float dr = Ar * dt, di = Ai * dt;
    float e  = expf(dr);
    float wr = e * cosf(di), wi = e * sinf(di);
    float Er = wr - 1.0f, Ei = wi;               // exp(dtA) - 1
    float inv = 1.0f / (Ar * Ar + Ai * Ai);
    float Fr = (Er * Ar + Ei * Ai) * inv;        // (exp(dtA)-1)/A
    float Fi = (Ei * Ar - Er * Ai) * inv;
    float ctr = 2.0f * (Cr * Fr - Ci * Fi);
    float cti = 2.0f * (Cr * Fi + Ci * Fr);
    float eq = expf((float)Q_ * dr);
    float ph = (float)Q_ * di;
    float wqr = eq * cosf(ph), wqi = eq * sinf(ph);
    float* pb = params + (size_t)lb * 6 * NH_;
    int o = n * H_ + h;
    pb[0 * NH_ + o] = wr;  pb[1 * NH_ + o] = wi;
    pb[2 * NH_ + o] = ctr; pb[3 * NH_ + o] = cti;
    pb[4 * NH_ + o] = wqr; pb[5 * NH_ + o] = wqi;
}

// ---------------- Encoder weight pack (interleaved complex -> real) ------
// WR'[n][2k]=Wr[n][k], WR'[n][2k+1]=-Wi[n][k]   (row n of Wp)
// WI'[n][2k]=Wi[n][k], WI'[n][2k+1]= Wr[n][k]   (row 256+n of Wp)
// so  accR = x_interleaved . WR'_n,  accI = x_interleaved . WI'_n
__global__ __launch_bounds__(256) void pack_enc(
        const void* __restrict__ Wr, const void* __restrict__ Wi,
        ushort_t* __restrict__ Wp, const int* __restrict__ dfl) {
    int f32 = *dfl;
    int n = blockIdx.x;
    for (int k = threadIdx.x; k < 260; k += 256) {
        float wr = 0.f, wi = 0.f;
        if (k < DIN_) {
            wr = ldi(Wr, (size_t)n * DIN_ + k, f32);
            wi = ldi(Wi, (size_t)n * DIN_ + k, f32);
        }
        Wp[(size_t)n * EPK_ + 2 * k]             = f2bf(wr);
        Wp[(size_t)n * EPK_ + 2 * k + 1]         = f2bf(-wi);
        Wp[(size_t)(256 + n) * EPK_ + 2 * k]     = f2bf(wi);
        Wp[(size_t)(256 + n) * EPK_ + 2 * k + 1] = f2bf(wr);
    }
}

// ---------------- Encoder: complex GEMM via interleaved-real MFMA --------
// A = raw x viewed as (BL x 514) reals [re0,im0,re1,...]; B = packed Wp.
// K main loop covers 512; the k=256 pair (kk=512,513) is a rank-1 complex
// update folded into the epilogue.
__global__ __launch_bounds__(256) void enc_gemm(
        const void* __restrict__ x, const ushort_t* __restrict__ Wp,
        const void* __restrict__ br, const void* __restrict__ bi,
        ushort_t* __restrict__ xr, ushort_t* __restrict__ xi,
        const int* __restrict__ dfl) {
    __shared__ __align__(16) ushort_t As[8192];   // x tile 128x64 (swizzled)
    __shared__ __align__(16) ushort_t Brs[4096];  // WR' tile 64x64
    __shared__ __align__(16) ushort_t Bis[4096];  // WI' tile 64x64
    int f32 = *dfl;
    int m0 = blockIdx.x * 128, n0 = blockIdx.y * 64;
    int tid = threadIdx.x;
    int w = tid >> 6, l = tid & 63;
    int rb = w * 32;
    int lr = l & 15, lk = (l >> 4) << 4, lsw = (l & 7) << 4;
    // A staging: 2 threads per row, 64B each
    int arow = tid >> 1;
    int ahalf = (tid & 1) << 6;
    int asw = (arow & 7) << 4;
    // B staging: 4 threads per row, 32B each
    int brow = tid >> 2;
    int bq = (tid & 3) << 5;
    int bsw = (brow & 7) << 4;
    f32x4 z4 = {0.f, 0.f, 0.f, 0.f};
    f32x4 aR[2][4], aI[2][4];
#pragma unroll
    for (int mi = 0; mi < 2; ++mi)
#pragma unroll
        for (int nj = 0; nj < 4; ++nj) { aR[mi][nj] = z4; aI[mi][nj] = z4; }

    for (int k0 = 0; k0 < 512; k0 += 64) {
        if (k0) __syncthreads();
        {   // A: 128 rows x 64 interleaved reals -> swizzled bf16 LDS
            char* pa = (char*)As + arow * 128;
            size_t xbase = (size_t)(m0 + arow) * 2 * DIN_ + k0;
#pragma unroll
            for (int cc = 0; cc < 4; ++cc) {
                int cb = ahalf + cc * 16;
                uint4 v = ld8r(x, xbase + (cb >> 1), f32);
                *(uint4*)(pa + (cb ^ asw)) = v;
            }
        }
        {   // B: packed weights, aligned uint4
            const ushort_t* wr_p = Wp + (size_t)(n0 + brow) * EPK_ + k0;
            const ushort_t* wi_p = Wp + (size_t)(256 + n0 + brow) * EPK_ + k0;
            char* pr_ = (char*)Brs + brow * 128;
            char* pi_ = (char*)Bis + brow * 128;
#pragma unroll
            for (int cc = 0; cc < 2; ++cc) {
                int cb = bq + cc * 16;
                *(uint4*)(pr_ + (cb ^ bsw)) = *(const uint4*)(wr_p + (cb >> 1));
                *(uint4*)(pi_ + (cb ^ bsw)) = *(const uint4*)(wi_p + (cb >> 1));
            }
        }
        __syncthreads();
#pragma unroll
        for (int ks = 0; ks < 2; ++ks) {
            int off = (ks * 64 + lk) ^ lsw;
            short8 a0 = *(const short8*)((const char*)As + (rb + lr) * 128 + off);
            short8 a1 = *(const short8*)((const char*)As + (rb + 16 + lr) * 128 + off);
#pragma unroll
            for (int nj = 0; nj < 4; ++nj) {
                short8 wr_ = *(const short8*)((const char*)Brs + (nj * 16 + lr) * 128 + off);
                short8 wi_ = *(const short8*)((const char*)Bis + (nj * 16 + lr) * 128 + off);
                aR[0][nj] = MFMA16(a0, wr_, aR[0][nj]);
                aR[1][nj] = MFMA16(a1, wr_, aR[1][nj]);
                aI[0][nj] = MFMA16(a0, wi_, aI[0][nj]);
                aI[1][nj] = MFMA16(a1, wi_, aI[1][nj]);
            }
        }
    }
    // k=256 remainder inputs (one complex pair per output row)
    float xre8[8], xim8[8];
#pragma unroll
    for (int mi = 0; mi < 2; ++mi)
#pragma unroll
        for (int r = 0; r < 4; ++r) {
            int row = m0 + rb + mi * 16 + ((l >> 4) << 2) + r;
            size_t pi = (size_t)row * DIN_ + 256;
            float re, im;
            if (f32) { float2 v = ((const float2*)x)[pi]; re = v.x; im = v.y; }
            else { uint_t v = ((const uint_t*)x)[pi];
                   re = bfu((ushort_t)(v & 0xFFFF)); im = bfu((ushort_t)(v >> 16)); }
            xre8[mi * 4 + r] = re; xim8[mi * 4 + r] = im;
        }
#pragma unroll
    for (int nj = 0; nj < 4; ++nj) {
        int col = n0 + nj * 16 + lr;
        float wRr = bfu(Wp[(size_t)col * EPK_ + 512]);
        float wRi = bfu(Wp[(size_t)col * EPK_ + 513]);
        float wIr = bfu(Wp[(size_t)(256 + col) * EPK_ + 512]);
        float wIi = bfu(Wp[(size_t)(256 + col) * EPK_ + 513]);
        float bR = ldi(br, col, f32), bI = ldi(bi, col, f32);
#pragma unroll
        for (int mi = 0; mi < 2; ++mi)
#pragma unroll
            for (int r = 0; r < 4; ++r) {
                int row = m0 + rb + mi * 16 + ((l >> 4) << 2) + r;
                int q = mi * 4 + r;
                float re = aR[mi][nj][r] + xre8[q] * wRr + xim8[q] * wRi + bR;
                float im = aI[mi][nj][r] + xre8[q] * wIr + xim8[q] * wIi + bI;
                size_t off = (size_t)row * H_ + col;
                xr[off] = f2bf(re);
                xi[off] = f2bf(im);
            }
    }
}

// ---------------- Pass A: per-chunk local state inject (states -> bf16) ---
__global__ __launch_bounds__(256) void pass_a(
        const ushort_t* __restrict__ U, const float* __restrict__ P, ushort_t* __restrict__ S) {
    int c = blockIdx.x, b = blockIdx.y, h = threadIdx.x;
    float wr[N_], wi[N_], sr[N_], si[N_];
#pragma unroll
    for (int n = 0; n < N_; ++n) {
        wr[n] = P[n * H_ + h]; wi[n] = P[NH_ + n * H_ + h];
        sr[n] = 0.f; si[n] = 0.f;
    }
    const ushort_t* u = U + (size_t)(b * L_ + c * Q_) * H_ + h;
    float uvn = bfu(u[0]);
    for (int t = 0; t < Q_; ++t) {
        float uv = uvn;
        int tn = (t + 1 < Q_) ? t + 1 : t;
        uvn = bfu(u[(size_t)tn * H_]);
#pragma unroll
        for (int n = 0; n < N_; ++n) {
            float nr = fmaf(wr[n], sr[n], fmaf(-wi[n], si[n], uv));
            si[n] = fmaf(wr[n], si[n], wi[n] * sr[n]);
            sr[n] = nr;
        }
    }
    size_t o = (size_t)(b * NC_ + c) * N_ * H_ + h;
#pragma unroll
    for (int n = 0; n < N_; ++n) {
        S[o + n * H_] = f2bf(sr[n]);
        S[o + n * H_ + SSZ_] = f2bf(si[n]);
    }
}

// ---------------- Pass B: chunk-level carry scan (in-place -> init state) -
__global__ __launch_bounds__(256) void pass_b(
        const float* __restrict__ P, ushort_t* __restrict__ S) {
    int n = blockIdx.x, b = blockIdx.y, h = threadIdx.x;
    float wqr = P[4 * NH_ + n * H_ + h], wqi = P[5 * NH_ + n * H_ + h];
    float Xr = 0.f, Xi = 0.f;
    for (int c = 0; c < NC_; ++c) {
        size_t idx = ((size_t)(b * NC_ + c) * N_ + n) * H_ + h;
        float lr = bfu(S[idx]), li = bfu(S[idx + SSZ_]);
        S[idx] = f2bf(Xr); S[idx + SSZ_] = f2bf(Xi);   // init state for chunk c
        float nr = fmaf(wqr, Xr, fmaf(-wqi, Xi, lr));
        Xi = fmaf(wqr, Xi, fmaf(wqi, Xr, li));
        Xr = nr;
    }
}

// ---------------- Pass C: scan w/ init + y=conv+D*u -> gelu --------------
__global__ __launch_bounds__(256) void pass_c(
        const ushort_t* __restrict__ U, const float* __restrict__ P,
        const ushort_t* __restrict__ S, const void* __restrict__ Dp, int doff,
        ushort_t* __restrict__ G, const int* __restrict__ dfl) {
    int f32 = *dfl;
    int c = blockIdx.x, b = blockIdx.y;
    int tid = threadIdx.x;
    int h = blockIdx.z * 128 + (tid >> 1);
    int nb = (tid & 1) * 16;
    float wr[16], wi[16], cr[16], ci[16], sr[16], si[16];
#pragma unroll
    for (int i = 0; i < 16; ++i) {
        int o = (nb + i) * H_ + h;
        wr[i] = P[o]; wi[i] = P[NH_ + o];
        cr[i] = P[2 * NH_ + o]; ci[i] = P[3 * NH_ + o];
    }
    size_t so = (size_t)(b * NC_ + c) * N_ * H_ + h;
#pragma unroll
    for (int i = 0; i < 16; ++i) {
        sr[i] = bfu(S[so + (nb + i) * H_]);
        si[i] = bfu(S[so + (nb + i) * H_ + SSZ_]);
    }
    float Dv = ldi(Dp, (size_t)doff + h, f32);
    const ushort_t* u = U + (size_t)(b * L_ + c * Q_) * H_ + h;
    ushort_t* g = G + (size_t)(b * L_ + c * Q_) * H_ + h;
    float uvn = bfu(u[0]);
    for (int t = 0; t < Q_; ++t) {
        float uv = uvn;
        int tn = (t + 1 < Q_) ? t + 1 : t;
        uvn = bfu(u[(size_t)tn * H_]);
        float a0 = 0.f, a1 = 0.f;
#pragma unroll
        for (int i = 0; i < 16; ++i) {
            float nr = fmaf(wr[i], sr[i], fmaf(-wi[i], si[i], uv));
            si[i] = fmaf(wr[i], si[i], wi[i] * sr[i]);
            sr[i] = nr;
            if (i & 1) a1 = fmaf(cr[i], sr[i], fmaf(-ci[i], si[i], a1));
            else       a0 = fmaf(cr[i], sr[i], fmaf(-ci[i], si[i], a0));
        }
        float acc = a0 + a1;
        acc += __shfl_xor(acc, 1, 64);           // combine the two 16-state halves
        float y = fmaf(Dv, uv, acc);
        float ge = 0.5f * y * (1.0f + erff(y * 0.70710678118654752f));
        if ((tid & 1) == 0) g[(size_t)t * H_] = f2bf(ge);
    }
}

// ---------------- Wout GEMM (MFMA) + bias + GLU, accumulate into z -------
// mode: 0 = store, 1 = add, 2 = sub
__global__ __launch_bounds__(256) void wout_gemm(
        const ushort_t* __restrict__ Gb, const void* __restrict__ W, size_t woff,
        const void* __restrict__ bo, int boff, ushort_t* __restrict__ Z, int mode,
        const int* __restrict__ dfl) {
    __shared__ __align__(16) ushort_t As[8192];   // 128 x 64 bf16 (swizzled)
    __shared__ __align__(16) ushort_t Bs[8192];   // 128 x 64 bf16 (swizzled)
    int f32 = *dfl;
    int m0 = blockIdx.x * 128, n0 = blockIdx.y * 64;
    int tid = threadIdx.x;
    int w = tid >> 6, l = tid & 63;
    int rb = w * 32;                              // wave's 32-row slice
    int lr = l & 15, lk = (l >> 4) << 4;          // frag row-in-16 / k-octet byte
    int lsw = (l & 7) << 4;                       // read-side swizzle
    // A-stage (global_load_lds, pre-swizzled source):
    int arow = tid >> 3;                          // 0..31 (+ch*32)
    int acb  = ((tid & 7) << 4) ^ ((arow & 7) << 4);  // logical colbyte at dest slot
    // B-stage (reg-staged, handles fp32-or-bf16 weights):
    int brow = tid >> 1;                          // 0..127
    int bhalf = (tid & 1) << 6;                   // colbyte 0 or 64
    int bsw = (brow & 7) << 4;
    int wrow = (brow < 64) ? (n0 + brow) : (192 + n0 + brow);  // a rows / g rows
    f32x4 z4 = {0.f, 0.f, 0.f, 0.f};
    f32x4 acc[2][8];
#pragma unroll
    for (int mi = 0; mi < 2; ++mi)
#pragma unroll
        for (int nj = 0; nj < 8; ++nj) acc[mi][nj] = z4;

    for (int k0 = 0; k0 < H_; k0 += 64) {
        if (k0) __syncthreads();
        {   // A: 128x64 bf16, 4 chunks of 256 lanes x 16B
            const ushort_t* src = Gb + (size_t)(m0 + arow) * H_ + k0 + (acb >> 1);
            ushort_t* dst = As + tid * 8;
#pragma unroll
            for (int ch = 0; ch < 4; ++ch)
                gl16(src + (size_t)ch * 32 * H_, dst + ch * 2048);
        }
        {   // B: W rows -> swizzled LDS (64B per thread)
            size_t wb = woff + (size_t)wrow * H_ + k0;
            char* bp = (char*)Bs + brow * 128;
#pragma unroll
            for (int cc = 0; cc < 4; ++cc) {
                int cb = bhalf + cc * 16;
                uint4 v = ld8bf(W, wb + (cb >> 1), f32);
                *(uint4*)(bp + (cb ^ bsw)) = v;
            }
        }
        __syncthreads();
#pragma unroll
        for (int ks = 0; ks < 2; ++ks) {
            int off = (ks * 64 + lk) ^ lsw;
            short8 a0 = *(const short8*)((const char*)As + (rb + lr) * 128 + off);
            short8 a1 = *(const short8*)((const char*)As + (rb + 16 + lr) * 128 + off);
#pragma unroll
            for (int nj = 0; nj < 8; ++nj) {
                short8 bv = *(const short8*)((const char*)Bs + (nj * 16 + lr) * 128 + off);
                acc[0][nj] = MFMA16(a0, bv, acc[0][nj]);
                acc[1][nj] = MFMA16(a1, bv, acc[1][nj]);
            }
        }
    }
    float ba[4], bg[4];
#pragma unroll
    for (int nj = 0; nj < 4; ++nj) {
        ba[nj] = ldi(bo, (size_t)boff + n0 + nj * 16 + lr, f32);
        bg[nj] = ldi(bo, (size_t)boff + 256 + n0 + nj * 16 + lr, f32);
    }
#pragma unroll
    for (int mi = 0; mi < 2; ++mi)
#pragma unroll
        for (int nj = 0; nj < 4; ++nj)
#pragma unroll
            for (int r = 0; r < 4; ++r) {
                float av = acc[mi][nj][r] + ba[nj];
                float gv = acc[mi][nj + 4][r] + bg[nj];
                float s = av * (1.0f / (1.0f + expf(-gv)));
                int row = m0 + rb + mi * 16 + ((l >> 4) << 2) + r;
                size_t zo = (size_t)row * H_ + n0 + nj * 16 + lr;
                if (mode == 0)      Z[zo] = f2bf(s);
                else if (mode == 1) Z[zo] = f2bf(bfu(Z[zo]) + s);
                else                Z[zo] = f2bf(bfu(Z[zo]) - s);
            }
}

// ---------------- residual + LayerNorm (both real & imag) ----------------
__global__ __launch_bounds__(256) void combine_ln(
        ushort_t* __restrict__ xr, ushort_t* __restrict__ xi,
        const ushort_t* __restrict__ zr, const ushort_t* __restrict__ zi,
        const void* __restrict__ gamma, const void* __restrict__ beta, int layer,
        const int* __restrict__ dfl) {
    __shared__ float red[4][4];
    int f32 = *dfl;
    int l = blockIdx.x, b = blockIdx.y, h = threadIdx.x;
    size_t row = (size_t)(b * L_ + l) * H_ + h;
    float vr = bfu(xr[row]) + bfu(zr[row]);
    float vi = bfu(xi[row]) + bfu(zi[row]);
    float s0 = vr, s1 = vr * vr, s2 = vi, s3 = vi * vi;
#pragma unroll
    for (int off = 32; off >= 1; off >>= 1) {
        s0 += __shfl_xor(s0, off, 64); s1 += __shfl_xor(s1, off, 64);
        s2 += __shfl_xor(s2, off, 64); s3 += __shfl_xor(s3, off, 64);
    }
    int wv = h >> 6;
    if ((h & 63) == 0) { red[wv][0] = s0; red[wv][1] = s1; red[wv][2] = s2; red[wv][3] = s3; }
    __syncthreads();
    float S0 = red[0][0] + red[1][0] + red[2][0] + red[3][0];
    float S1 = red[0][1] + red[1][1] + red[2][1] + red[3][1];
    float S2 = red[0][2] + red[1][2] + red[2][2] + red[3][2];
    float S3 = red[0][3] + red[1][3] + red[2][3] + red[3][3];
    const float invH = 1.0f / 256.0f;
    float mur = S0 * invH, varr = S1 * invH - mur * mur;
    float mui = S2 * invH, vari = S3 * invH - mui * mui;
    float gr = ldi(gamma, (size_t)(layer * 2 + 0) * H_ + h, f32);
    float br_ = ldi(beta, (size_t)(layer * 2 + 0) * H_ + h, f32);
    float gi = ldi(gamma, (size_t)(layer * 2 + 1) * H_ + h, f32);
    float bi_ = ldi(beta, (size_t)(layer * 2 + 1) * H_ + h, f32);
    xr[row] = f2bf((vr - mur) * rsqrtf(varr + 1e-5f) * gr + br_);
    xi[row] = f2bf((vi - mui) * rsqrtf(vari + 1e-5f) * gi + bi_);
}

// ---------------- Decoder: complex GEMM (MFMA) (BL x 256) -> 257 ---------
__global__ __launch_bounds__(256) void dec_gemm(
        const ushort_t* __restrict__ xr, const ushort_t* __restrict__ xi,
        const void* __restrict__ Wr, const void* __restrict__ Wi,
        const void* __restrict__ br, const void* __restrict__ bi,
        void* __restrict__ out, const int* __restrict__ dfl) {
    __shared__ __align__(16) ushort_t Ars[8192];  // xr tile 128x64
    __shared__ __align__(16) ushort_t Ais[8192];  // xi tile 128x64
    __shared__ __align__(16) ushort_t Brs[4096];  // Wr tile  64x64
    __shared__ __align__(16) ushort_t Bis[4096];  // Wi tile  64x64
    int f32 = *dfl;
    int m0 = blockIdx.x * 128, n0 = blockIdx.y * 64;
    int tid = threadIdx.x;
    int w = tid >> 6, l = tid & 63;
    int rb = w * 32;
    int lr = l & 15, lk = (l >> 4) << 4, lsw = (l & 7) << 4;
    int arow = tid >> 3;
    int acb  = ((tid & 7) << 4) ^ ((arow & 7) << 4);
    int brow = tid >> 2;                          // 0..63
    int bq   = (tid & 3) << 5;                    // colbyte 0/32/64/96
    int bsw  = (brow & 7) << 4;
    int wrow = n0 + brow;
    bool bvalid = wrow < DOUT_;
    uint4 zz; zz.x = zz.y = zz.z = zz.w = 0u;
    f32x4 z4 = {0.f, 0.f, 0.f, 0.f};
    f32x4 aR[2][4], aI[2][4];
#pragma unroll
    for (int mi = 0; mi < 2; ++mi)
#pragma unroll
        for (int nj = 0; nj < 4; ++nj) { aR[mi][nj] = z4; aI[mi][nj] = z4; }

    for (int k0 = 0; k0 < H_; k0 += 64) {
        if (k0) __syncthreads();
        {   // A: xr and xi tiles via global_load_lds (pre-swizzled source)
            size_t so = (size_t)(m0 + arow) * H_ + k0 + (acb >> 1);
            ushort_t* dr = Ars + tid * 8;
            ushort_t* di = Ais + tid * 8;
#pragma unroll
            for (int ch = 0; ch < 4; ++ch) {
                gl16(xr + so + (size_t)ch * 32 * H_, dr + ch * 2048);
                gl16(xi + so + (size_t)ch * 32 * H_, di + ch * 2048);
            }
        }
        {   // B: Wr/Wi rows -> swizzled LDS, zero-fill past row 256
            size_t wb = (size_t)wrow * H_ + k0 + (bq >> 1);
            char* pr_ = (char*)Brs + brow * 128;
            char* pi_ = (char*)Bis + brow * 128;
#pragma unroll
            for (int cc = 0; cc < 2; ++cc) {
                int cb = bq + cc * 16;
                uint4 vr = zz, vi = zz;
                if (bvalid) {
                    vr = ld8bf(Wr, wb + cc * 8, f32);
                    vi = ld8bf(Wi, wb + cc * 8, f32);
                }
                *(uint4*)(pr_ + (cb ^ bsw)) = vr;
                *(uint4*)(pi_ + (cb ^ bsw)) = vi;
            }
        }
        __syncthreads();
#pragma unroll
        for (int ks = 0; ks < 2; ++ks) {
            int off = (ks * 64 + lk) ^ lsw;
            short8 x0 = *(const short8*)((const char*)Ars + (rb + lr) * 128 + off);
            short8 x1 = *(const short8*)((const char*)Ars + (rb + 16 + lr) * 128 + off);
            short8 y0 = *(const short8*)((const char*)Ais + (rb + lr) * 128 + off);
            short8 y1 = *(const short8*)((const char*)Ais + (rb + 16 + lr) * 128 + off);
#pragma unroll
            for (int nj = 0; nj < 4; ++nj) {
                short8 wr_ = *(const short8*)((const char*)Brs + (nj * 16 + lr) * 128 + off);
                short8 wi_ = *(const short8*)((const char*)Bis + (nj * 16 + lr) * 128 + off);
                short8 wn = negbf(wi_);
                aR[0][nj] = MFMA16(x0, wr_, aR[0][nj]);
                aR[0][nj] = MFMA16(y0, wn,  aR[0][nj]);
                aR[1][nj] = MFMA16(x1, wr_, aR[1][nj]);
                aR[1][nj] = MFMA16(y1, wn,  aR[1][nj]);
                aI[0][nj] = MFMA16(x0, wi_, aI[0][nj]);
                aI[0][nj] = MFMA16(y0, wr_, aI[0][nj]);
                aI[1][nj] = MFMA16(x1, wi_, aI[1][nj]);
                aI[1][nj] = MFMA16(y1, wr_, aI[1][nj]);
            }
        }
    }
#pragma unroll
    for (int nj = 0; nj < 4; ++nj) {
        int col = n0 + nj * 16 + lr;
        if (col < DOUT_) {
            float bR = ldi(br, col, f32), bI = ldi(bi, col, f32);
#pragma unroll
            for (int mi = 0; mi < 2; ++mi)
#pragma unroll
                for (int r = 0; r < 4; ++r) {
                    int row = m0 + rb + mi * 16 + ((l >> 4) << 2) + r;
                    size_t pi = (size_t)row * DOUT_ + col;
                    float re = aR[mi][nj][r] + bR;
                    float im = aI[mi][nj][r] + bI;
                    if (f32) {
                        ((float2*)out)[pi] = make_float2(re, im);
                    } else {
                        ((uint_t*)out)[pi] = (uint_t)f2bf(re) | ((uint_t)f2bf(im) << 16);
                    }
                }
        }
    }
}

// -------------------------------------------------------------------------
extern "C" void kernel_launch(void* const* d_in, const int* in_sizes, int n_in,
                              void* d_out, int out_size, void* d_ws, size_t ws_size,
                              hipStream_t stream) {
    const void* x      = d_in[0];
    const void* enc_Wr = d_in[1];
    const void* enc_Wi = d_in[2];
    const void* enc_br = d_in[3];
    const void* enc_bi = d_in[4];
    const void* log_dt = d_in[5];
    const void* lAr    = d_in[6];
    const void* Aim    = d_in[7];
    const void* C2     = d_in[8];
    const void* Dp     = d_in[9];
    const void* Wout   = d_in[10];
    const void* bout   = d_in[11];
    const void* gamma  = d_in[12];
    const void* beta   = d_in[13];
    const void* dec_Wr = d_in[14];
    const void* dec_Wi = d_in[15];
    const void* dec_br = d_in[16];
    const void* dec_bi = d_in[17];

    // ws layout (~113.6 MiB):
    //   xr (32M) | xi (32M) | gb (32M) | st bf16 (16M) | flag | pr fp32 (1.5M)
    // zr/zi live in d_out (dead until dec_gemm rewrites every element last)
    // st doubles as the packed enc-weight buffer before the layer loop.
    ushort_t* xr = (ushort_t*)d_ws;
    ushort_t* xi = xr + (size_t)PLANE_;
    ushort_t* gb = xi + (size_t)PLANE_;
    ushort_t* st = gb + (size_t)PLANE_;
    int*      fl = (int*)(st + (size_t)2 * SSZ_);
    float*    pr = (float*)(fl + 64);            // 256-byte pad for alignment
    ushort_t* zr = (ushort_t*)d_out;
    ushort_t* zi = zr + (size_t)PLANE_;
    ushort_t* Wp = st;                           // 512 x 520 bf16 = 532 KB

    probe_kernel<<<1, 256, 0, stream>>>(x, fl);
    param_kernel<<<256, 256, 0, stream>>>(log_dt, lAr, Aim, C2, pr, fl);
    pack_enc<<<256, 256, 0, stream>>>(enc_Wr, enc_Wi, Wp, fl);
    enc_gemm<<<dim3(BL_ / 128, H_ / 64), 256, 0, stream>>>(x, Wp, enc_br, enc_bi, xr, xi, fl);

    for (int l = 0; l < NL_; ++l) {
        // zr = sr(xr) - si(xi);  zi = sr(xi) + si(xr)
        struct App { int br; const ushort_t* U; ushort_t* Zt; int mode; };
        App apps[4] = {
            {0, xr, zr, 0},   // sr(xr) -> zr (store)
            {1, xi, zr, 2},   // si(xi) -> zr (sub)
            {0, xi, zi, 0},   // sr(xi) -> zi (store)
            {1, xr, zi, 1},   // si(xr) -> zi (add)
        };
        for (int a = 0; a < 4; ++a) {
            const float* P = pr + (size_t)(l * 2 + apps[a].br) * 6 * NH_;
            pass_a<<<dim3(NC_, B_), 256, 0, stream>>>(apps[a].U, P, st);
            pass_b<<<dim3(N_, B_), 256, 0, stream>>>(P, st);
            pass_c<<<dim3(NC_, B_, 2), 256, 0, stream>>>(apps[a].U, P, st,
                    Dp, (l * 2 + apps[a].br) * H_, gb, fl);
            wout_gemm<<<dim3(BL_ / 128, H_ / 64), 256, 0, stream>>>(gb,
                    Wout, (size_t)(l * 2 + apps[a].br) * 512 * H_,
                    bout, (l * 2 + apps[a].br) * 512,
                    apps[a].Zt, apps[a].mode, fl);
        }
        combine_ln<<<dim3(L_, B_), 256, 0, stream>>>(xr, xi, zr, zi, gamma, beta, l, fl);
    }

    dec_gemm<<<dim3(BL_ / 128, (DOUT_ + 63) / 64), 256, 0, stream>>>(
            xr, xi, dec_Wr, dec_Wi, dec_br, dec_bi, d_out, fl);
}

// Round 3
// 4509.472 us; speedup vs baseline: 1.8096x; 1.0366x over previous
//
#include <hip/hip_runtime.h>

typedef unsigned short ushort_t;
typedef unsigned int uint_t;
typedef __attribute__((ext_vector_type(8))) short short8;   // 8 bf16 (4 VGPR) MFMA frag
typedef __attribute__((ext_vector_type(4))) float f32x4;    // MFMA accumulator frag

#define B_    16
#define L_    4096
#define H_    256
#define N_    32
#define DIN_  257
#define DOUT_ 257
#define NL_   4
#define Q_    128
#define NC_   32                 // L_/Q_
#define BL_   (B_*L_)            // 65536
#define NH_   (N_*H_)            // 8192
#define PLANE_ 16777216          // BL_*H_
#define SSZ_  4194304            // B_*NC_*N_*H_ (elements)

__device__ __forceinline__ float bfu(ushort_t u) {
    union { uint_t i; float f; } v; v.i = ((uint_t)u) << 16; return v.f;
}
__device__ __forceinline__ ushort_t f2bf(float f) {
    union { float f; uint_t i; } v; v.f = f;
    uint_t x = v.i;
    return (ushort_t)((x + 0x7FFFu + ((x >> 16) & 1u)) >> 16);
}
__device__ __forceinline__ uint2 pack4(float a, float b, float c, float d) {
    uint2 r;
    r.x = (uint_t)f2bf(a) | ((uint_t)f2bf(b) << 16);
    r.y = (uint_t)f2bf(c) | ((uint_t)f2bf(d) << 16);
    return r;
}
// dtype-flexible external-input load: f32!=0 -> fp32, else bf16
__device__ __forceinline__ float ldi(const void* p, size_t i, int f32) {
    return f32 ? ((const float*)p)[i] : bfu(((const ushort_t*)p)[i]);
}

// async global->LDS, 16B per lane (dest = wave-uniform base + lane*16)
__device__ __forceinline__ void gl16(const ushort_t* g, ushort_t* l) {
    __builtin_amdgcn_global_load_lds(
        (const __attribute__((address_space(1))) uint_t*)g,
        (__attribute__((address_space(3))) uint_t*)l, 16, 0, 0);
}

// load 8 source weights (fp32 or bf16) as packed bf16x8 (uint4); 16B-aligned src
__device__ __forceinline__ uint4 ld8bf(const void* W, size_t eoff, int f32) {
    uint4 r;
    if (f32) {
        const float* p = (const float*)W + eoff;
        float4 a = *(const float4*)p;
        float4 b = *(const float4*)(p + 4);
        r.x = (uint_t)f2bf(a.x) | ((uint_t)f2bf(a.y) << 16);
        r.y = (uint_t)f2bf(a.z) | ((uint_t)f2bf(a.w) << 16);
        r.z = (uint_t)f2bf(b.x) | ((uint_t)f2bf(b.y) << 16);
        r.w = (uint_t)f2bf(b.z) | ((uint_t)f2bf(b.w) << 16);
    } else {
        r = *(const uint4*)((const ushort_t*)W + eoff);
    }
    return r;
}

// negate 8 packed bf16 (sign-bit flip) -> used for -xi*Wi accumulation
__device__ __forceinline__ short8 negbf(short8 v) {
    short8 r;
#pragma unroll
    for (int i = 0; i < 8; ++i) r[i] = (short)(v[i] ^ (short)0x8000);
    return r;
}

#define MFMA16(a, b, c) __builtin_amdgcn_mfma_f32_16x16x32_bf16((a), (b), (c), 0, 0, 0)

// ---------------- dtype probe --------------------------------------------
__global__ void probe_kernel(const void* __restrict__ x, int* __restrict__ flag) {
    __shared__ int cnt;
    if (threadIdx.x == 0) cnt = 0;
    __syncthreads();
    uint_t w = ((const uint_t*)x)[threadIdx.x];
    float f = bfu((ushort_t)(w & 0xFFFF));
    float a = fabsf(f);
    if (a > 1e-5f && a < 100.f) atomicAdd(&cnt, 1);
    __syncthreads();
    if (threadIdx.x == 0) *flag = (cnt > 128) ? 0 : 1;  // 0 = bf16, 1 = fp32
}

// ---------------- SSM parameter precompute -------------------------------
__global__ __launch_bounds__(256) void param_kernel(
        const void* __restrict__ log_dt, const void* __restrict__ lAr,
        const void* __restrict__ Aim, const void* __restrict__ C2,
        float* __restrict__ params, const int* __restrict__ dfl) {
    int f32 = *dfl;
    int idx = blockIdx.x * 256 + threadIdx.x;   // over NL_*2*N_*H_ = 65536
    int h  = idx & (H_ - 1);
    int n  = (idx >> 8) & (N_ - 1);
    int lb = idx >> 13;                          // layer*2+branch
    float dt = expf(ldi(log_dt, lb * H_ + h, f32));
    size_t pin = (size_t)(lb * H_ + h) * N_ + n;
    float Ar = -expf(ldi(lAr, pin, f32));
    float Ai = ldi(Aim, pin, f32);
    float Cr = ldi(C2, pin * 2, f32), Ci = ldi(C2, pin * 2 + 1, f32);
    float dr = Ar * dt, di = Ai * dt;
    float e  = expf(dr);
    float wr = e * cosf(di), wi = e * sinf(di);
    float Er = wr - 1.0f, Ei = wi;               // exp(dtA) - 1
    float inv = 1.0f / (Ar * Ar + Ai * Ai);
    float Fr = (Er * Ar + Ei * Ai) * inv;        // (exp(dtA)-1)/A
    float Fi = (Ei * Ar - Er * Ai) * inv;
    float ctr = 2.0f * (Cr * Fr - Ci * Fi);
    float cti = 2.0f * (Cr * Fi + Ci * Fr);
    float eq = expf((float)Q_ * dr);
    float ph = (float)Q_ * di;
    float wqr = eq * cosf(ph), wqi = eq * sinf(ph);
    float* pb = params + (size_t)lb * 6 * NH_;
    int o = n * H_ + h;
    pb[0 * NH_ + o] = wr;  pb[1 * NH_ + o] = wi;
    pb[2 * NH_ + o] = ctr; pb[3 * NH_ + o] = cti;
    pb[4 * NH_ + o] = wqr; pb[5 * NH_ + o] = wqi;
}

// ---------------- x repack: deinterleave cols 0..255 into bf16 planes ----
__global__ __launch_bounds__(256) void repack_x(
        const void* __restrict__ x, ushort_t* __restrict__ xre,
        ushort_t* __restrict__ xim, const int* __restrict__ dfl) {
    int f32 = *dfl;
    size_t i = ((size_t)blockIdx.x * 256 + threadIdx.x) * 4;  // over BL_*256
    int row = (int)(i >> 8);
    int k = (int)(i & 255);                                   // <= 252
    size_t src = (size_t)row * DIN_ + k;
    float re[4], im[4];
#pragma unroll
    for (int j = 0; j < 4; ++j) {
        if (f32) {
            float2 v = ((const float2*)x)[src + j];
            re[j] = v.x; im[j] = v.y;
        } else {
            uint_t v = ((const uint_t*)x)[src + j];
            re[j] = bfu((ushort_t)(v & 0xFFFF));
            im[j] = bfu((ushort_t)(v >> 16));
        }
    }
    *(uint2*)(xre + i) = pack4(re[0], re[1], re[2], re[3]);
    *(uint2*)(xim + i) = pack4(im[0], im[1], im[2], im[3]);
}

// ---------------- enc weight pack: cols 0..255 -> aligned bf16 [256][256] -
__global__ __launch_bounds__(256) void pack_encw(
        const void* __restrict__ Wr, const void* __restrict__ Wi,
        ushort_t* __restrict__ Wpr, ushort_t* __restrict__ Wpi,
        const int* __restrict__ dfl) {
    int f32 = *dfl;
    int n = blockIdx.x, k = threadIdx.x;
    Wpr[n * 256 + k] = f2bf(ldi(Wr, (size_t)n * DIN_ + k, f32));
    Wpi[n * 256 + k] = f2bf(ldi(Wi, (size_t)n * DIN_ + k, f32));
}

// ---------------- Encoder: complex GEMM (MFMA), dec_gemm structure -------
// accR = xre*Wr^T - xim*Wi^T ; accI = xre*Wi^T + xim*Wr^T  over k=0..255,
// plus the ragged k=256 column as a rank-1 complex update in the epilogue.
__global__ __launch_bounds__(256) void enc_gemm(
        const ushort_t* __restrict__ xre, const ushort_t* __restrict__ xim,
        const ushort_t* __restrict__ Wpr, const ushort_t* __restrict__ Wpi,
        const void* __restrict__ x, const void* __restrict__ eWr,
        const void* __restrict__ eWi, const void* __restrict__ br,
        const void* __restrict__ bi, ushort_t* __restrict__ xr,
        ushort_t* __restrict__ xi_, const int* __restrict__ dfl) {
    __shared__ __align__(16) ushort_t Ars[8192];  // xre tile 128x64
    __shared__ __align__(16) ushort_t Ais[8192];  // xim tile 128x64
    __shared__ __align__(16) ushort_t Brs[4096];  // Wr tile  64x64
    __shared__ __align__(16) ushort_t Bis[4096];  // Wi tile  64x64
    int f32 = *dfl;
    int m0 = blockIdx.x * 128, n0 = blockIdx.y * 64;
    int tid = threadIdx.x;
    int w = tid >> 6, l = tid & 63;
    int rb = w * 32;
    int lr = l & 15, lk = (l >> 4) << 4, lsw = (l & 7) << 4;
    int arow = tid >> 3;
    int acb  = ((tid & 7) << 4) ^ ((arow & 7) << 4);
    int brow = tid >> 2;                          // 0..63
    int bq   = (tid & 3) << 5;                    // colbyte 0/32/64/96
    int bsw  = (brow & 7) << 4;
    int wrow = n0 + brow;                         // always < 256
    f32x4 z4 = {0.f, 0.f, 0.f, 0.f};
    f32x4 aR[2][4], aI[2][4];
#pragma unroll
    for (int mi = 0; mi < 2; ++mi)
#pragma unroll
        for (int nj = 0; nj < 4; ++nj) { aR[mi][nj] = z4; aI[mi][nj] = z4; }

    for (int k0 = 0; k0 < H_; k0 += 64) {
        if (k0) __syncthreads();
        {   // A: xre and xim tiles via global_load_lds (pre-swizzled source)
            size_t so = (size_t)(m0 + arow) * H_ + k0 + (acb >> 1);
            ushort_t* dr = Ars + tid * 8;
            ushort_t* di = Ais + tid * 8;
#pragma unroll
            for (int ch = 0; ch < 4; ++ch) {
                gl16(xre + so + (size_t)ch * 32 * H_, dr + ch * 2048);
                gl16(xim + so + (size_t)ch * 32 * H_, di + ch * 2048);
            }
        }
        {   // B: packed bf16 weights, aligned uint4
            char* pr_ = (char*)Brs + brow * 128;
            char* pi_ = (char*)Bis + brow * 128;
#pragma unroll
            for (int cc = 0; cc < 2; ++cc) {
                int cb = bq + cc * 16;
                *(uint4*)(pr_ + (cb ^ bsw)) =
                    *(const uint4*)(Wpr + (size_t)wrow * H_ + k0 + (cb >> 1));
                *(uint4*)(pi_ + (cb ^ bsw)) =
                    *(const uint4*)(Wpi + (size_t)wrow * H_ + k0 + (cb >> 1));
            }
        }
        __syncthreads();
#pragma unroll
        for (int ks = 0; ks < 2; ++ks) {
            int off = (ks * 64 + lk) ^ lsw;
            short8 x0 = *(const short8*)((const char*)Ars + (rb + lr) * 128 + off);
            short8 x1 = *(const short8*)((const char*)Ars + (rb + 16 + lr) * 128 + off);
            short8 y0 = *(const short8*)((const char*)Ais + (rb + lr) * 128 + off);
            short8 y1 = *(const short8*)((const char*)Ais + (rb + 16 + lr) * 128 + off);
#pragma unroll
            for (int nj = 0; nj < 4; ++nj) {
                short8 wr_ = *(const short8*)((const char*)Brs + (nj * 16 + lr) * 128 + off);
                short8 wi_ = *(const short8*)((const char*)Bis + (nj * 16 + lr) * 128 + off);
                short8 wn = negbf(wi_);
                aR[0][nj] = MFMA16(x0, wr_, aR[0][nj]);
                aR[0][nj] = MFMA16(y0, wn,  aR[0][nj]);
                aR[1][nj] = MFMA16(x1, wr_, aR[1][nj]);
                aR[1][nj] = MFMA16(y1, wn,  aR[1][nj]);
                aI[0][nj] = MFMA16(x0, wi_, aI[0][nj]);
                aI[0][nj] = MFMA16(y0, wr_, aI[0][nj]);
                aI[1][nj] = MFMA16(x1, wi_, aI[1][nj]);
                aI[1][nj] = MFMA16(y1, wr_, aI[1][nj]);
            }
        }
    }
    // ragged k=256 column inputs (one complex pair per output row)
    float xcr[8], xci[8];
#pragma unroll
    for (int mi = 0; mi < 2; ++mi)
#pragma unroll
        for (int r = 0; r < 4; ++r) {
            int row = m0 + rb + mi * 16 + ((l >> 4) << 2) + r;
            size_t pi = (size_t)row * DIN_ + 256;
            float re, im;
            if (f32) { float2 v = ((const float2*)x)[pi]; re = v.x; im = v.y; }
            else { uint_t v = ((const uint_t*)x)[pi];
                   re = bfu((ushort_t)(v & 0xFFFF)); im = bfu((ushort_t)(v >> 16)); }
            xcr[mi * 4 + r] = re; xci[mi * 4 + r] = im;
        }
#pragma unroll
    for (int nj = 0; nj < 4; ++nj) {
        int col = n0 + nj * 16 + lr;
        float wcr = ldi(eWr, (size_t)col * DIN_ + 256, f32);
        float wci = ldi(eWi, (size_t)col * DIN_ + 256, f32);
        float bR = ldi(br, col, f32), bI = ldi(bi, col, f32);
#pragma unroll
        for (int mi = 0; mi < 2; ++mi)
#pragma unroll
            for (int r = 0; r < 4; ++r) {
                int row = m0 + rb + mi * 16 + ((l >> 4) << 2) + r;
                int q = mi * 4 + r;
                float re = aR[mi][nj][r] + xcr[q] * wcr - xci[q] * wci + bR;
                float im = aI[mi][nj][r] + xcr[q] * wci + xci[q] * wcr + bI;
                size_t off = (size_t)row * H_ + col;
                xr[off]  = f2bf(re);
                xi_[off] = f2bf(im);
            }
    }
}

// ---------------- Pass A: per-chunk local state inject (states -> bf16) ---
// U chunk-tile (128 x 256 bf16 = 64 KB, contiguous in U) staged to LDS via
// global_load_lds; the t-loop then reads LDS only (no per-t HBM latency).
__global__ __launch_bounds__(256) void pass_a(
        const ushort_t* __restrict__ U, const float* __restrict__ P, ushort_t* __restrict__ S) {
    __shared__ __align__(16) ushort_t Us[Q_ * H_];   // 64 KB
    int c = blockIdx.x, b = blockIdx.y, h = threadIdx.x;
    const ushort_t* ub = U + (size_t)(b * L_ + c * Q_) * H_;
#pragma unroll
    for (int p = 0; p < 16; ++p)
        gl16(ub + p * 2048 + h * 8, Us + p * 2048 + h * 8);
    float wr[N_], wi[N_], sr[N_], si[N_];
#pragma unroll
    for (int n = 0; n < N_; ++n) {
        wr[n] = P[n * H_ + h]; wi[n] = P[NH_ + n * H_ + h];
        sr[n] = 0.f; si[n] = 0.f;
    }
    __syncthreads();
    float uvn = bfu(Us[h]);
    for (int t = 0; t < Q_; ++t) {
        float uv = uvn;
        int tn = (t + 1 < Q_) ? t + 1 : t;
        uvn = bfu(Us[tn * H_ + h]);
#pragma unroll
        for (int n = 0; n < N_; ++n) {
            float nr = fmaf(wr[n], sr[n], fmaf(-wi[n], si[n], uv));
            si[n] = fmaf(wr[n], si[n], wi[n] * sr[n]);
            sr[n] = nr;
        }
    }
    size_t o = (size_t)(b * NC_ + c) * N_ * H_ + h;
#pragma unroll
    for (int n = 0; n < N_; ++n) {
        S[o + n * H_] = f2bf(sr[n]);
        S[o + n * H_ + SSZ_] = f2bf(si[n]);
    }
}

// ---------------- Pass B: chunk-level carry scan (in-place -> init state) -
__global__ __launch_bounds__(256) void pass_b(
        const float* __restrict__ P, ushort_t* __restrict__ S) {
    int n = blockIdx.x, b = blockIdx.y, h = threadIdx.x;
    float wqr = P[4 * NH_ + n * H_ + h], wqi = P[5 * NH_ + n * H_ + h];
    float Xr = 0.f, Xi = 0.f;
    for (int c = 0; c < NC_; ++c) {
        size_t idx = ((size_t)(b * NC_ + c) * N_ + n) * H_ + h;
        float lr = bfu(S[idx]), li = bfu(S[idx + SSZ_]);
        S[idx] = f2bf(Xr); S[idx + SSZ_] = f2bf(Xi);   // init state for chunk c
        float nr = fmaf(wqr, Xr, fmaf(-wqi, Xi, lr));
        Xi = fmaf(wqr, Xi, fmaf(wqi, Xr, li));
        Xr = nr;
    }
}

// ---------------- Pass C: scan w/ init + y=conv+D*u -> gelu --------------
// U half-tile (128 x 128 bf16 = 32 KB) staged to LDS via global_load_lds.
__global__ __launch_bounds__(256) void pass_c(
        const ushort_t* __restrict__ U, const float* __restrict__ P,
        const ushort_t* __restrict__ S, const void* __restrict__ Dp, int doff,
        ushort_t* __restrict__ G, const int* __restrict__ dfl) {
    __shared__ __align__(16) ushort_t Us[Q_ * 128];  // 32 KB
    int f32 = *dfl;
    int c = blockIdx.x, b = blockIdx.y;
    int tid = threadIdx.x;
    int wv = tid >> 6, l = tid & 63;
    int hl = tid >> 1;                    // local h 0..127
    int h = blockIdx.z * 128 + hl;
    int nb = (tid & 1) * 16;
    const ushort_t* ub = U + (size_t)(b * L_ + c * Q_) * H_ + blockIdx.z * 128;
#pragma unroll
    for (int p = 0; p < 8; ++p) {
        int row = p * 16 + wv * 4 + (l >> 4);
        gl16(ub + (size_t)row * H_ + (l & 15) * 8,
             Us + (p * 16 + wv * 4) * 128 + l * 8);
    }
    float wr[16], wi[16], cr[16], ci[16], sr[16], si[16];
#pragma unroll
    for (int i = 0; i < 16; ++i) {
        int o = (nb + i) * H_ + h;
        wr[i] = P[o]; wi[i] = P[NH_ + o];
        cr[i] = P[2 * NH_ + o]; ci[i] = P[3 * NH_ + o];
    }
    size_t so = (size_t)(b * NC_ + c) * N_ * H_ + h;
#pragma unroll
    for (int i = 0; i < 16; ++i) {
        sr[i] = bfu(S[so + (nb + i) * H_]);
        si[i] = bfu(S[so + (nb + i) * H_ + SSZ_]);
    }
    float Dv = ldi(Dp, (size_t)doff + h, f32);
    ushort_t* g = G + (size_t)(b * L_ + c * Q_) * H_ + h;
    __syncthreads();
    float uvn = bfu(Us[hl]);
    for (int t = 0; t < Q_; ++t) {
        float uv = uvn;
        int tn = (t + 1 < Q_) ? t + 1 : t;
        uvn = bfu(Us[tn * 128 + hl]);
        float a0 = 0.f, a1 = 0.f;
#pragma unroll
        for (int i = 0; i < 16; ++i) {
            float nr = fmaf(wr[i], sr[i], fmaf(-wi[i], si[i], uv));
            si[i] = fmaf(wr[i], si[i], wi[i] * sr[i]);
            sr[i] = nr;
            if (i & 1) a1 = fmaf(cr[i], sr[i], fmaf(-ci[i], si[i], a1));
            else       a0 = fmaf(cr[i], sr[i], fmaf(-ci[i], si[i], a0));
        }
        float acc = a0 + a1;
        acc += __shfl_xor(acc, 1, 64);           // combine the two 16-state halves
        float y = fmaf(Dv, uv, acc);
        float ge = 0.5f * y * (1.0f + erff(y * 0.70710678118654752f));
        if ((tid & 1) == 0) g[(size_t)t * H_] = f2bf(ge);
    }
}

// ---------------- Wout GEMM (MFMA) + bias + GLU, accumulate into z -------
// mode: 0 = store, 1 = add, 2 = sub
__global__ __launch_bounds__(256) void wout_gemm(
        const ushort_t* __restrict__ Gb, const void* __restrict__ W, size_t woff,
        const void* __restrict__ bo, int boff, ushort_t* __restrict__ Z, int mode,
        const int* __restrict__ dfl) {
    __shared__ __align__(16) ushort_t As[8192];   // 128 x 64 bf16 (swizzled)
    __shared__ __align__(16) ushort_t Bs[8192];   // 128 x 64 bf16 (swizzled)
    int f32 = *dfl;
    int m0 = blockIdx.x * 128, n0 = blockIdx.y * 64;
    int tid = threadIdx.x;
    int w = tid >> 6, l = tid & 63;
    int rb = w * 32;                              // wave's 32-row slice
    int lr = l & 15, lk = (l >> 4) << 4;          // frag row-in-16 / k-octet byte
    int lsw = (l & 7) << 4;                       // read-side swizzle
    // A-stage (global_load_lds, pre-swizzled source):
    int arow = tid >> 3;                          // 0..31 (+ch*32)
    int acb  = ((tid & 7) << 4) ^ ((arow & 7) << 4);  // logical colbyte at dest slot
    // B-stage (reg-staged, handles fp32-or-bf16 weights):
    int brow = tid >> 1;                          // 0..127
    int bhalf = (tid & 1) << 6;                   // colbyte 0 or 64
    int bsw = (brow & 7) << 4;
    int wrow = (brow < 64) ? (n0 + brow) : (192 + n0 + brow);  // a rows / g rows
    f32x4 z4 = {0.f, 0.f, 0.f, 0.f};
    f32x4 acc[2][8];
#pragma unroll
    for (int mi = 0; mi < 2; ++mi)
#pragma unroll
        for (int nj = 0; nj < 8; ++nj) acc[mi][nj] = z4;

    for (int k0 = 0; k0 < H_; k0 += 64) {
        if (k0) __syncthreads();
        {   // A: 128x64 bf16, 4 chunks of 256 lanes x 16B
            const ushort_t* src = Gb + (size_t)(m0 + arow) * H_ + k0 + (acb >> 1);
            ushort_t* dst = As + tid * 8;
#pragma unroll
            for (int ch = 0; ch < 4; ++ch)
                gl16(src + (size_t)ch * 32 * H_, dst + ch * 2048);
        }
        {   // B: W rows -> swizzled LDS (64B per thread)
            size_t wb = woff + (size_t)wrow * H_ + k0;
            char* bp = (char*)Bs + brow * 128;
#pragma unroll
            for (int cc = 0; cc < 4; ++cc) {
                int cb = bhalf + cc * 16;
                uint4 v = ld8bf(W, wb + (cb >> 1), f32);
                *(uint4*)(bp + (cb ^ bsw)) = v;
            }
        }
        __syncthreads();
#pragma unroll
        for (int ks = 0; ks < 2; ++ks) {
            int off = (ks * 64 + lk) ^ lsw;
            short8 a0 = *(const short8*)((const char*)As + (rb + lr) * 128 + off);
            short8 a1 = *(const short8*)((const char*)As + (rb + 16 + lr) * 128 + off);
#pragma unroll
            for (int nj = 0; nj < 8; ++nj) {
                short8 bv = *(const short8*)((const char*)Bs + (nj * 16 + lr) * 128 + off);
                acc[0][nj] = MFMA16(a0, bv, acc[0][nj]);
                acc[1][nj] = MFMA16(a1, bv, acc[1][nj]);
            }
        }
    }
    float ba[4], bg[4];
#pragma unroll
    for (int nj = 0; nj < 4; ++nj) {
        ba[nj] = ldi(bo, (size_t)boff + n0 + nj * 16 + lr, f32);
        bg[nj] = ldi(bo, (size_t)boff + 256 + n0 + nj * 16 + lr, f32);
    }
#pragma unroll
    for (int mi = 0; mi < 2; ++mi)
#pragma unroll
        for (int nj = 0; nj < 4; ++nj)
#pragma unroll
            for (int r = 0; r < 4; ++r) {
                float av = acc[mi][nj][r] + ba[nj];
                float gv = acc[mi][nj + 4][r] + bg[nj];
                float s = av * (1.0f / (1.0f + expf(-gv)));
                int row = m0 + rb + mi * 16 + ((l >> 4) << 2) + r;
                size_t zo = (size_t)row * H_ + n0 + nj * 16 + lr;
                if (mode == 0)      Z[zo] = f2bf(s);
                else if (mode == 1) Z[zo] = f2bf(bfu(Z[zo]) + s);
                else                Z[zo] = f2bf(bfu(Z[zo]) - s);
            }
}

// ---------------- residual + LayerNorm (both real & imag) ----------------
__global__ __launch_bounds__(256) void combine_ln(
        ushort_t* __restrict__ xr, ushort_t* __restrict__ xi,
        const ushort_t* __restrict__ zr, const ushort_t* __restrict__ zi,
        const void* __restrict__ gamma, const void* __restrict__ beta, int layer,
        const int* __restrict__ dfl) {
    __shared__ float red[4][4];
    int f32 = *dfl;
    int l = blockIdx.x, b = blockIdx.y, h = threadIdx.x;
    size_t row = (size_t)(b * L_ + l) * H_ + h;
    float vr = bfu(xr[row]) + bfu(zr[row]);
    float vi = bfu(xi[row]) + bfu(zi[row]);
    float s0 = vr, s1 = vr * vr, s2 = vi, s3 = vi * vi;
#pragma unroll
    for (int off = 32; off >= 1; off >>= 1) {
        s0 += __shfl_xor(s0, off, 64); s1 += __shfl_xor(s1, off, 64);
        s2 += __shfl_xor(s2, off, 64); s3 += __shfl_xor(s3, off, 64);
    }
    int wv = h >> 6;
    if ((h & 63) == 0) { red[wv][0] = s0; red[wv][1] = s1; red[wv][2] = s2; red[wv][3] = s3; }
    __syncthreads();
    float S0 = red[0][0] + red[1][0] + red[2][0] + red[3][0];
    float S1 = red[0][1] + red[1][1] + red[2][1] + red[3][1];
    float S2 = red[0][2] + red[1][2] + red[2][2] + red[3][2];
    float S3 = red[0][3] + red[1][3] + red[2][3] + red[3][3];
    const float invH = 1.0f / 256.0f;
    float mur = S0 * invH, varr = S1 * invH - mur * mur;
    float mui = S2 * invH, vari = S3 * invH - mui * mui;
    float gr = ldi(gamma, (size_t)(layer * 2 + 0) * H_ + h, f32);
    float br_ = ldi(beta, (size_t)(layer * 2 + 0) * H_ + h, f32);
    float gi = ldi(gamma, (size_t)(layer * 2 + 1) * H_ + h, f32);
    float bi_ = ldi(beta, (size_t)(layer * 2 + 1) * H_ + h, f32);
    xr[row] = f2bf((vr - mur) * rsqrtf(varr + 1e-5f) * gr + br_);
    xi[row] = f2bf((vi - mui) * rsqrtf(vari + 1e-5f) * gi + bi_);
}

// ---------------- Decoder: complex GEMM (MFMA) (BL x 256) -> 257 ---------
__global__ __launch_bounds__(256) void dec_gemm(
        const ushort_t* __restrict__ xr, const ushort_t* __restrict__ xi,
        const void* __restrict__ Wr, const void* __restrict__ Wi,
        const void* __restrict__ br, const void* __restrict__ bi,
        void* __restrict__ out, const int* __restrict__ dfl) {
    __shared__ __align__(16) ushort_t Ars[8192];  // xr tile 128x64
    __shared__ __align__(16) ushort_t Ais[8192];  // xi tile 128x64
    __shared__ __align__(16) ushort_t Brs[4096];  // Wr tile  64x64
    __shared__ __align__(16) ushort_t Bis[4096];  // Wi tile  64x64
    int f32 = *dfl;
    int m0 = blockIdx.x * 128, n0 = blockIdx.y * 64;
    int tid = threadIdx.x;
    int w = tid >> 6, l = tid & 63;
    int rb = w * 32;
    int lr = l & 15, lk = (l >> 4) << 4, lsw = (l & 7) << 4;
    int arow = tid >> 3;
    int acb  = ((tid & 7) << 4) ^ ((arow & 7) << 4);
    int brow = tid >> 2;                          // 0..63
    int bq   = (tid & 3) << 5;                    // colbyte 0/32/64/96
    int bsw  = (brow & 7) << 4;
    int wrow = n0 + brow;
    bool bvalid = wrow < DOUT_;
    uint4 zz; zz.x = zz.y = zz.z = zz.w = 0u;
    f32x4 z4 = {0.f, 0.f, 0.f, 0.f};
    f32x4 aR[2][4], aI[2][4];
#pragma unroll
    for (int mi = 0; mi < 2; ++mi)
#pragma unroll
        for (int nj = 0; nj < 4; ++nj) { aR[mi][nj] = z4; aI[mi][nj] = z4; }

    for (int k0 = 0; k0 < H_; k0 += 64) {
        if (k0) __syncthreads();
        {   // A: xr and xi tiles via global_load_lds (pre-swizzled source)
            size_t so = (size_t)(m0 + arow) * H_ + k0 + (acb >> 1);
            ushort_t* dr = Ars + tid * 8;
            ushort_t* di = Ais + tid * 8;
#pragma unroll
            for (int ch = 0; ch < 4; ++ch) {
                gl16(xr + so + (size_t)ch * 32 * H_, dr + ch * 2048);
                gl16(xi + so + (size_t)ch * 32 * H_, di + ch * 2048);
            }
        }
        {   // B: Wr/Wi rows -> swizzled LDS, zero-fill past row 256
            size_t wb = (size_t)wrow * H_ + k0 + (bq >> 1);
            char* pr_ = (char*)Brs + brow * 128;
            char* pi_ = (char*)Bis + brow * 128;
#pragma unroll
            for (int cc = 0; cc < 2; ++cc) {
                int cb = bq + cc * 16;
                uint4 vr = zz, vi = zz;
                if (bvalid) {
                    vr = ld8bf(Wr, wb + cc * 8, f32);
                    vi = ld8bf(Wi, wb + cc * 8, f32);
                }
                *(uint4*)(pr_ + (cb ^ bsw)) = vr;
                *(uint4*)(pi_ + (cb ^ bsw)) = vi;
            }
        }
        __syncthreads();
#pragma unroll
        for (int ks = 0; ks < 2; ++ks) {
            int off = (ks * 64 + lk) ^ lsw;
            short8 x0 = *(const short8*)((const char*)Ars + (rb + lr) * 128 + off);
            short8 x1 = *(const short8*)((const char*)Ars + (rb + 16 + lr) * 128 + off);
            short8 y0 = *(const short8*)((const char*)Ais + (rb + lr) * 128 + off);
            short8 y1 = *(const short8*)((const char*)Ais + (rb + 16 + lr) * 128 + off);
#pragma unroll
            for (int nj = 0; nj < 4; ++nj) {
                short8 wr_ = *(const short8*)((const char*)Brs + (nj * 16 + lr) * 128 + off);
                short8 wi_ = *(const short8*)((const char*)Bis + (nj * 16 + lr) * 128 + off);
                short8 wn = negbf(wi_);
                aR[0][nj] = MFMA16(x0, wr_, aR[0][nj]);
                aR[0][nj] = MFMA16(y0, wn,  aR[0][nj]);
                aR[1][nj] = MFMA16(x1, wr_, aR[1][nj]);
                aR[1][nj] = MFMA16(y1, wn,  aR[1][nj]);
                aI[0][nj] = MFMA16(x0, wi_, aI[0][nj]);
                aI[0][nj] = MFMA16(y0, wr_, aI[0][nj]);
                aI[1][nj] = MFMA16(x1, wi_, aI[1][nj]);
                aI[1][nj] = MFMA16(y1, wr_, aI[1][nj]);
            }
        }
    }
#pragma unroll
    for (int nj = 0; nj < 4; ++nj) {
        int col = n0 + nj * 16 + lr;
        if (col < DOUT_) {
            float bR = ldi(br, col, f32), bI = ldi(bi, col, f32);
#pragma unroll
            for (int mi = 0; mi < 2; ++mi)
#pragma unroll
                for (int r = 0; r < 4; ++r) {
                    int row = m0 + rb + mi * 16 + ((l >> 4) << 2) + r;
                    size_t pi = (size_t)row * DOUT_ + col;
                    float re = aR[mi][nj][r] + bR;
                    float im = aI[mi][nj][r] + bI;
                    if (f32) {
                        ((float2*)out)[pi] = make_float2(re, im);
                    } else {
                        ((uint_t*)out)[pi] = (uint_t)f2bf(re) | ((uint_t)f2bf(im) << 16);
                    }
                }
        }
    }
}

// -------------------------------------------------------------------------
extern "C" void kernel_launch(void* const* d_in, const int* in_sizes, int n_in,
                              void* d_out, int out_size, void* d_ws, size_t ws_size,
                              hipStream_t stream) {
    const void* x      = d_in[0];
    const void* enc_Wr = d_in[1];
    const void* enc_Wi = d_in[2];
    const void* enc_br = d_in[3];
    const void* enc_bi = d_in[4];
    const void* log_dt = d_in[5];
    const void* lAr    = d_in[6];
    const void* Aim    = d_in[7];
    const void* C2     = d_in[8];
    const void* Dp     = d_in[9];
    const void* Wout   = d_in[10];
    const void* bout   = d_in[11];
    const void* gamma  = d_in[12];
    const void* beta   = d_in[13];
    const void* dec_Wr = d_in[14];
    const void* dec_Wi = d_in[15];
    const void* dec_br = d_in[16];
    const void* dec_bi = d_in[17];

    // ws layout (~113.6 MiB):
    //   xr (32M) | xi (32M) | gb (32M) | st bf16 (16M) | flag | pr fp32 (1.5M)
    // zr/zi live in d_out (dead until dec_gemm rewrites every element last);
    // before the layer loop they double as repacked-x planes, and the head of
    // st doubles as the packed bf16 enc-weight buffer.
    ushort_t* xr = (ushort_t*)d_ws;
    ushort_t* xi = xr + (size_t)PLANE_;
    ushort_t* gb = xi + (size_t)PLANE_;
    ushort_t* st = gb + (size_t)PLANE_;
    int*      fl = (int*)(st + (size_t)2 * SSZ_);
    float*    pr = (float*)(fl + 64);            // 256-byte pad for alignment
    ushort_t* zr = (ushort_t*)d_out;
    ushort_t* zi = zr + (size_t)PLANE_;
    ushort_t* xre = zr;                          // repacked x planes (pre-loop)
    ushort_t* xim = zi;
    ushort_t* Wpr = st;                          // packed enc weights (pre-loop)
    ushort_t* Wpi = st + 65536;

    probe_kernel<<<1, 256, 0, stream>>>(x, fl);
    param_kernel<<<256, 256, 0, stream>>>(log_dt, lAr, Aim, C2, pr, fl);
    repack_x<<<16384, 256, 0, stream>>>(x, xre, xim, fl);
    pack_encw<<<256, 256, 0, stream>>>(enc_Wr, enc_Wi, Wpr, Wpi, fl);
    enc_gemm<<<dim3(BL_ / 128, H_ / 64), 256, 0, stream>>>(xre, xim, Wpr, Wpi,
            x, enc_Wr, enc_Wi, enc_br, enc_bi, xr, xi, fl);

    for (int l = 0; l < NL_; ++l) {
        // zr = sr(xr) - si(xi);  zi = sr(xi) + si(xr)
        struct App { int br; const ushort_t* U; ushort_t* Zt; int mode; };
        App apps[4] = {
            {0, xr, zr, 0},   // sr(xr) -> zr (store)
            {1, xi, zr, 2},   // si(xi) -> zr (sub)
            {0, xi, zi, 0},   // sr(xi) -> zi (store)
            {1, xr, zi, 1},   // si(xr) -> zi (add)
        };
        for (int a = 0; a < 4; ++a) {
            const float* P = pr + (size_t)(l * 2 + apps[a].br) * 6 * NH_;
            pass_a<<<dim3(NC_, B_), 256, 0, stream>>>(apps[a].U, P, st);
            pass_b<<<dim3(N_, B_), 256, 0, stream>>>(P, st);
            pass_c<<<dim3(NC_, B_, 2), 256, 0, stream>>>(apps[a].U, P, st,
                    Dp, (l * 2 + apps[a].br) * H_, gb, fl);
            wout_gemm<<<dim3(BL_ / 128, H_ / 64), 256, 0, stream>>>(gb,
                    Wout, (size_t)(l * 2 + apps[a].br) * 512 * H_,
                    bout, (l * 2 + apps[a].br) * 512,
                    apps[a].Zt, apps[a].mode, fl);
        }
        combine_ln<<<dim3(L_, B_), 256, 0, stream>>>(xr, xi, zr, zi, gamma, beta, l, fl);
    }

    dec_gemm<<<dim3(BL_ / 128, (DOUT_ + 63) / 64), 256, 0, stream>>>(
            xr, xi, dec_Wr, dec_Wi, dec_br, dec_bi, d_out, fl);
}